// Round 2
// baseline (722.289 us; speedup 1.0000x reference)
//
#include <hip/hip_runtime.h>
#include <hip/hip_bf16.h>
#include <math.h>

// ---------------- CSR build ----------------

__global__ void init_k(int* __restrict__ deg, int* __restrict__ fill,
                       float* __restrict__ g, int n) {
    int i = blockIdx.x * blockDim.x + threadIdx.x;
    if (i < n) { deg[i] = 1; fill[i] = 0; }   // deg starts at 1: self loop
    if (i < 66) g[i] = 0.f;
}

__global__ void hist_k(const int* __restrict__ ei, int* __restrict__ deg, int E) {
    int i = blockIdx.x * blockDim.x + threadIdx.x;
    if (i < E) atomicAdd(&deg[ei[E + i]], 1);   // dst row of edge_index
}

__global__ void scan_block_k(const int* __restrict__ deg, int* __restrict__ offs,
                             int* __restrict__ bsum, int n) {
    __shared__ int ls[1024];
    int t = threadIdx.x;
    int i = blockIdx.x * 1024 + t;
    int v = (i < n) ? deg[i] : 0;
    ls[t] = v;
    __syncthreads();
    for (int off = 1; off < 1024; off <<= 1) {
        int add = (t >= off) ? ls[t - off] : 0;
        __syncthreads();
        ls[t] += add;
        __syncthreads();
    }
    if (i < n) offs[i] = ls[t] - v;          // exclusive scan (partial)
    if (t == 1023) bsum[blockIdx.x] = ls[1023];
}

__global__ void scan_tops_k(int* __restrict__ bsum, int nb) {
    __shared__ int ls[128];
    int t = threadIdx.x;
    int v = (t < nb) ? bsum[t] : 0;
    ls[t] = v;
    __syncthreads();
    for (int off = 1; off < 128; off <<= 1) {
        int add = (t >= off) ? ls[t - off] : 0;
        __syncthreads();
        ls[t] += add;
        __syncthreads();
    }
    if (t < nb) bsum[t] = ls[t] - v;         // exclusive block offsets
}

__global__ void scan_add_k(int* __restrict__ offs, const int* __restrict__ bsum,
                           int n, int total) {
    int i = blockIdx.x * blockDim.x + threadIdx.x;
    if (i < n) offs[i] += bsum[i >> 10];
    if (i == 0) offs[n] = total;
}

__global__ void scatter_k(const int* __restrict__ ei, int* __restrict__ fill,
                          const int* __restrict__ offs, int* __restrict__ csr,
                          int E, int n) {
    int i = blockIdx.x * blockDim.x + threadIdx.x;
    int total = E + n;
    if (i >= total) return;
    int s, d;
    if (i < E) { s = ei[i]; d = ei[E + i]; }
    else       { s = d = i - E; }            // self loop
    int pos = offs[d] + atomicAdd(&fill[d], 1);
    csr[pos] = s;
}

// ---------------- GEMM: Y[M,NCOL] = X[M,128] @ W[128,NCOL] ----------------

template<int NCOL>
__global__ __launch_bounds__(256) void gemm_k128(const float* __restrict__ X,
                                                 const float* __restrict__ W,
                                                 float* __restrict__ Y, int M) {
    constexpr int TX  = NCOL / 8;    // 16 (NCOL=128) or 8 (NCOL=64)
    constexpr int TY  = 256 / TX;    // 16 or 32
    constexpr int RPT = 64 / TY;     // 4 or 2 rows per thread
    __shared__ float xs[64][65];     // pad -> bank-conflict-free column reads
    __shared__ float ws[64][NCOL];
    const int t    = threadIdx.x;
    const int row0 = blockIdx.x * 64;
    const int tx   = t % TX, ty = t / TX;
    float acc[RPT][8];
#pragma unroll
    for (int i = 0; i < RPT; i++)
#pragma unroll
        for (int j = 0; j < 8; j++) acc[i][j] = 0.f;

    for (int kb = 0; kb < 128; kb += 64) {
        for (int idx = t; idx < 64 * NCOL; idx += 256) {
            int kk = idx / NCOL, c = idx % NCOL;
            ws[kk][c] = W[(size_t)(kb + kk) * NCOL + c];
        }
        for (int idx = t; idx < 64 * 64; idx += 256) {
            int r = idx >> 6, kk = idx & 63;
            int gr = row0 + r;
            xs[r][kk] = (gr < M) ? X[(size_t)gr * 128 + kb + kk] : 0.f;
        }
        __syncthreads();
#pragma unroll 8
        for (int kk = 0; kk < 64; kk++) {
            float wv[8];
#pragma unroll
            for (int j = 0; j < 8; j++) wv[j] = ws[kk][tx * 8 + j];
#pragma unroll
            for (int i = 0; i < RPT; i++) {
                float xv = xs[ty * RPT + i][kk];
#pragma unroll
                for (int j = 0; j < 8; j++) acc[i][j] = fmaf(xv, wv[j], acc[i][j]);
            }
        }
        __syncthreads();
    }
    for (int i = 0; i < RPT; i++) {
        int gr = row0 + ty * RPT + i;
        if (gr < M) {
#pragma unroll
            for (int j = 0; j < 8; j++)
                Y[(size_t)gr * NCOL + tx * 8 + j] = acc[i][j];
        }
    }
}

// ---------------- per-node attention coefficients ----------------
// alpha_src[i][h] = sum_c H[i][h*C+c] * a_src[h*C+c]   (likewise dst)

template<int NCOL>
__global__ void alpha_k(const float* __restrict__ H, const float* __restrict__ asrc,
                        const float* __restrict__ adst, float* __restrict__ As,
                        float* __restrict__ Ad, int n) {
    int wid  = (blockIdx.x * blockDim.x + threadIdx.x) >> 6;
    int lane = threadIdx.x & 63;
    if (wid >= n) return;
    const float* hr = H + (size_t)wid * NCOL;
    if (NCOL == 128) {
        float h0 = hr[lane], h1 = hr[lane + 64];
        float s0 = h0 * asrc[lane], s1 = h1 * asrc[lane + 64];
        float d0 = h0 * adst[lane], d1 = h1 * adst[lane + 64];
        for (int m = 16; m >= 1; m >>= 1) {   // reduce within 32-lane head group
            s0 += __shfl_xor(s0, m); s1 += __shfl_xor(s1, m);
            d0 += __shfl_xor(d0, m); d1 += __shfl_xor(d1, m);
        }
        if ((lane & 31) == 0) {
            int h = lane >> 5;
            As[wid * 4 + h] = s0;  As[wid * 4 + 2 + h] = s1;
            Ad[wid * 4 + h] = d0;  Ad[wid * 4 + 2 + h] = d1;
        }
    } else {  // NCOL == 64, 16 channels/head
        float hv = hr[lane];
        float s = hv * asrc[lane], d = hv * adst[lane];
        for (int m = 8; m >= 1; m >>= 1) {    // reduce within 16-lane head group
            s += __shfl_xor(s, m); d += __shfl_xor(d, m);
        }
        if ((lane & 15) == 0) {
            int h = lane >> 4;
            As[wid * 4 + h] = s;  Ad[wid * 4 + h] = d;
        }
    }
}

// ---------------- edge aggregation: one wave per destination node ----------------
// out[i] = ( sum_{e: dst=i} exp(leaky(asrc[src]+adst[i])) * h[src] ) / sum exp(...)
// (segment-max subtraction dropped: ratio is invariant, |e| small -> fp32 safe)

template<int NCOL, bool RELU>
__global__ void aggregate_k(const float* __restrict__ H, const float* __restrict__ As,
                            const float* __restrict__ Ad, const int* __restrict__ offs,
                            const int* __restrict__ csr, const float* __restrict__ bias,
                            float* __restrict__ Out, int n) {
    int wid  = (blockIdx.x * blockDim.x + threadIdx.x) >> 6;
    int lane = threadIdx.x & 63;
    if (wid >= n) return;
    int beg = offs[wid], end = offs[wid + 1];
    if (NCOL == 128) {
        int h0 = lane >> 5, h1 = 2 + (lane >> 5);
        float ad0 = Ad[wid * 4 + h0], ad1 = Ad[wid * 4 + h1];
        float acc0 = 0.f, acc1 = 0.f, sw0 = 0.f, sw1 = 0.f;
        for (int e = beg; e < end; ++e) {
            int s = csr[e];
            float e0 = As[s * 4 + h0] + ad0; e0 = e0 > 0.f ? e0 : 0.2f * e0;
            float e1 = As[s * 4 + h1] + ad1; e1 = e1 > 0.f ? e1 : 0.2f * e1;
            float w0 = __expf(e0), w1 = __expf(e1);
            sw0 += w0; sw1 += w1;
            const float* hr = H + (size_t)s * 128;
            acc0 = fmaf(w0, hr[lane],      acc0);
            acc1 = fmaf(w1, hr[lane + 64], acc1);
        }
        float o0 = acc0 / sw0 + bias[lane];
        float o1 = acc1 / sw1 + bias[lane + 64];
        if (RELU) { o0 = fmaxf(o0, 0.f); o1 = fmaxf(o1, 0.f); }
        Out[(size_t)wid * 128 + lane]      = o0;
        Out[(size_t)wid * 128 + lane + 64] = o1;
    } else {  // NCOL == 64
        int h = lane >> 4;
        float ad = Ad[wid * 4 + h];
        float acc = 0.f, sw = 0.f;
        for (int e = beg; e < end; ++e) {
            int s = csr[e];
            float ev = As[s * 4 + h] + ad; ev = ev > 0.f ? ev : 0.2f * ev;
            float w = __expf(ev);
            sw += w;
            acc = fmaf(w, H[(size_t)s * 64 + lane], acc);
        }
        float o = acc / sw + bias[lane];
        if (RELU) o = fmaxf(o, 0.f);
        Out[(size_t)wid * 64 + lane] = o;
    }
}

// ---------------- global add pool + FC ----------------

__global__ void pool_k(const float* __restrict__ h2, float* __restrict__ g, int n) {
    __shared__ float ls[256];
    int c   = threadIdx.x & 63;
    int rg  = (blockIdx.x * blockDim.x + threadIdx.x) >> 6;
    int nrg = (gridDim.x * blockDim.x) >> 6;
    float acc = 0.f;
    for (int r = rg; r < n; r += nrg) acc += h2[(size_t)r * 64 + c];
    ls[threadIdx.x] = acc;
    __syncthreads();
    if (threadIdx.x < 64) {
        float v = ls[threadIdx.x] + ls[threadIdx.x + 64] +
                  ls[threadIdx.x + 128] + ls[threadIdx.x + 192];
        atomicAdd(&g[c], v);
    }
}

__global__ void fc_k(const float* __restrict__ g, const float* __restrict__ w,
                     const float* __restrict__ b, float* __restrict__ out) {
    int j = threadIdx.x;
    if (j < 2) {
        float acc = b[j];
        for (int c = 0; c < 64; c++) acc = fmaf(g[c], w[c * 2 + j], acc);
        out[j] = acc;
    }
}

// ---------------- launch ----------------

static inline size_t align256(size_t x) { return (x + 255) & ~(size_t)255; }

extern "C" void kernel_launch(void* const* d_in, const int* in_sizes, int n_in,
                              void* d_out, int out_size, void* d_ws, size_t ws_size,
                              hipStream_t stream) {
    const float* x     = (const float*)d_in[0];
    const int*   ei    = (const int*)  d_in[1];
    const float* W1    = (const float*)d_in[2];
    const float* asrc1 = (const float*)d_in[3];
    const float* adst1 = (const float*)d_in[4];
    const float* b1    = (const float*)d_in[5];
    const float* W2    = (const float*)d_in[6];
    const float* asrc2 = (const float*)d_in[7];
    const float* adst2 = (const float*)d_in[8];
    const float* b2    = (const float*)d_in[9];
    const float* fcw   = (const float*)d_in[10];
    const float* fcb   = (const float*)d_in[11];
    float* out = (float*)d_out;

    const int N = in_sizes[0] / 128;
    const int E = in_sizes[1] / 2;
    const int TOT = E + N;

    // workspace carve-up
    char* w = (char*)d_ws;
    size_t off = 0;
    int* deg  = (int*)(w + off); off = align256(off + (size_t)N * 4);
    int* fill = (int*)(w + off); off = align256(off + (size_t)N * 4);
    int* offs = (int*)(w + off); off = align256(off + (size_t)(N + 1) * 4);
    int* bsum = (int*)(w + off); off = align256(off + 256 * 4);
    int* csr  = (int*)(w + off); off = align256(off + (size_t)TOT * 4);
    float* As = (float*)(w + off); off = align256(off + (size_t)N * 4 * 4);
    float* Ad = (float*)(w + off); off = align256(off + (size_t)N * 4 * 4);
    float* g  = (float*)(w + off); off = align256(off + 66 * 4);
    float* bufH = (float*)(w + off); off = align256(off + (size_t)N * 128 * 4); // h1 then h2
    float* bufO = (float*)(w + off); off = align256(off + (size_t)N * 128 * 4); // out1 then out2

    const int nb = (N + 1023) / 1024;

    // --- build CSR (by dst, self loops included) ---
    init_k<<<(N + 255) / 256, 256, 0, stream>>>(deg, fill, g, N);
    hist_k<<<(E + 255) / 256, 256, 0, stream>>>(ei, deg, E);
    scan_block_k<<<nb, 1024, 0, stream>>>(deg, offs, bsum, N);
    scan_tops_k<<<1, 128, 0, stream>>>(bsum, nb);
    scan_add_k<<<(N + 255) / 256, 256, 0, stream>>>(offs, bsum, N, TOT);
    scatter_k<<<(TOT + 255) / 256, 256, 0, stream>>>(ei, fill, offs, csr, E, N);

    // --- layer 1 ---
    gemm_k128<128><<<(N + 63) / 64, 256, 0, stream>>>(x, W1, bufH, N);
    alpha_k<128><<<(N * 64 + 255) / 256, 256, 0, stream>>>(bufH, asrc1, adst1, As, Ad, N);
    aggregate_k<128, true><<<(N * 64 + 255) / 256, 256, 0, stream>>>(
        bufH, As, Ad, offs, csr, b1, bufO, N);

    // --- layer 2 ---
    gemm_k128<64><<<(N + 63) / 64, 256, 0, stream>>>(bufO, W2, bufH, N);
    alpha_k<64><<<(N * 64 + 255) / 256, 256, 0, stream>>>(bufH, asrc2, adst2, As, Ad, N);
    aggregate_k<64, false><<<(N * 64 + 255) / 256, 256, 0, stream>>>(
        bufH, As, Ad, offs, csr, b2, bufO, N);

    // --- pool + fc ---
    pool_k<<<256, 256, 0, stream>>>(bufO, g, N);
    fc_k<<<1, 64, 0, stream>>>(g, fcw, fcb, out);
}

// Round 3
// 586.256 us; speedup vs baseline: 1.2320x; 1.2320x over previous
//
#include <hip/hip_runtime.h>
#include <hip/hip_bf16.h>
#include <math.h>

// ---------------- bf16 helpers ----------------

__device__ __forceinline__ float b2f(unsigned short u) {
    return __uint_as_float(((unsigned)u) << 16);
}
__device__ __forceinline__ unsigned short f2b(float f) {
    unsigned x = __float_as_uint(f);
    return (unsigned short)((x + 0x7fffu + ((x >> 16) & 1u)) >> 16);  // RNE
}

struct alignas(16) us8 { unsigned short v[8]; };

// ---------------- CSR build ----------------

__global__ void init_k(int* __restrict__ deg, int* __restrict__ fill,
                       float* __restrict__ g, int n) {
    int i = blockIdx.x * blockDim.x + threadIdx.x;
    if (i < n) { deg[i] = 1; fill[i] = 0; }   // deg starts at 1: self loop
    if (i < 66) g[i] = 0.f;
}

__global__ void hist_k(const int* __restrict__ ei, int* __restrict__ deg, int E) {
    int i = blockIdx.x * blockDim.x + threadIdx.x;
    if (i < E) atomicAdd(&deg[ei[E + i]], 1);   // dst row of edge_index
}

__global__ void scan_block_k(const int* __restrict__ deg, int* __restrict__ offs,
                             int* __restrict__ bsum, int n) {
    __shared__ int ls[1024];
    int t = threadIdx.x;
    int i = blockIdx.x * 1024 + t;
    int v = (i < n) ? deg[i] : 0;
    ls[t] = v;
    __syncthreads();
    for (int off = 1; off < 1024; off <<= 1) {
        int add = (t >= off) ? ls[t - off] : 0;
        __syncthreads();
        ls[t] += add;
        __syncthreads();
    }
    if (i < n) offs[i] = ls[t] - v;          // exclusive scan (partial)
    if (t == 1023) bsum[blockIdx.x] = ls[1023];
}

__global__ void scan_tops_k(int* __restrict__ bsum, int nb) {
    __shared__ int ls[128];
    int t = threadIdx.x;
    int v = (t < nb) ? bsum[t] : 0;
    ls[t] = v;
    __syncthreads();
    for (int off = 1; off < 128; off <<= 1) {
        int add = (t >= off) ? ls[t - off] : 0;
        __syncthreads();
        ls[t] += add;
        __syncthreads();
    }
    if (t < nb) bsum[t] = ls[t] - v;         // exclusive block offsets
}

__global__ void scan_add_k(int* __restrict__ offs, const int* __restrict__ bsum,
                           int n, int total) {
    int i = blockIdx.x * blockDim.x + threadIdx.x;
    if (i < n) offs[i] += bsum[i >> 10];
    if (i == 0) offs[n] = total;
}

__global__ void scatter_k(const int* __restrict__ ei, int* __restrict__ fill,
                          const int* __restrict__ offs, int* __restrict__ csr,
                          int E, int n) {
    int i = blockIdx.x * blockDim.x + threadIdx.x;
    int total = E + n;
    if (i >= total) return;
    int s, d;
    if (i < E) { s = ei[i]; d = ei[E + i]; }
    else       { s = d = i - E; }            // self loop
    int pos = offs[d] + atomicAdd(&fill[d], 1);
    csr[pos] = s;
}

// ------- GEMM: Y[M,NCOL](bf16) = X[M,128] @ W[128,NCOL], fused alpha dots -------
// alpha_src[r][h] = sum_c Y[r][h*C+c]*asrc[h*C+c]  computed from fp32 acc in epilogue.

template<int NCOL, bool XBF16>
__global__ __launch_bounds__(256) void gemm_alpha_k(
        const void* __restrict__ Xv, const float* __restrict__ W,
        const float* __restrict__ asrc, const float* __restrict__ adst,
        unsigned short* __restrict__ Y, float* __restrict__ As,
        float* __restrict__ Ad, int M) {
    constexpr int TX  = NCOL / 8;        // 16 or 8
    constexpr int TY  = 256 / TX;        // 16 or 32
    constexpr int RPT = 64 / TY;         // 4 or 2 rows per thread
    constexpr int TPH = (NCOL == 128) ? 4 : 2;  // threads covering one head's channels
    __shared__ float xs[64][65];
    __shared__ float ws[64][NCOL];
    const int t    = threadIdx.x;
    const int row0 = blockIdx.x * 64;
    const int tx   = t % TX, ty = t / TX;
    float acc[RPT][8];
#pragma unroll
    for (int i = 0; i < RPT; i++)
#pragma unroll
        for (int j = 0; j < 8; j++) acc[i][j] = 0.f;

    for (int kb = 0; kb < 128; kb += 64) {
        for (int idx = t; idx < 64 * NCOL; idx += 256) {
            int kk = idx / NCOL, c = idx % NCOL;
            ws[kk][c] = W[(size_t)(kb + kk) * NCOL + c];
        }
        if constexpr (XBF16) {
            const unsigned short* Xb = (const unsigned short*)Xv;
            for (int idx = t; idx < 64 * 32; idx += 256) {
                int r = idx >> 5, k2 = (idx & 31) * 2;
                int gr = row0 + r;
                float v0 = 0.f, v1 = 0.f;
                if (gr < M) {
                    ushort2 u = *(const ushort2*)&Xb[(size_t)gr * 128 + kb + k2];
                    v0 = b2f(u.x); v1 = b2f(u.y);
                }
                xs[r][k2] = v0; xs[r][k2 + 1] = v1;
            }
        } else {
            const float* X = (const float*)Xv;
            for (int idx = t; idx < 64 * 64; idx += 256) {
                int r = idx >> 6, kk = idx & 63;
                int gr = row0 + r;
                xs[r][kk] = (gr < M) ? X[(size_t)gr * 128 + kb + kk] : 0.f;
            }
        }
        __syncthreads();
#pragma unroll 8
        for (int kk = 0; kk < 64; kk++) {
            float wv[8];
#pragma unroll
            for (int j = 0; j < 8; j++) wv[j] = ws[kk][tx * 8 + j];
#pragma unroll
            for (int i = 0; i < RPT; i++) {
                float xv = xs[ty * RPT + i][kk];
#pragma unroll
                for (int j = 0; j < 8; j++) acc[i][j] = fmaf(xv, wv[j], acc[i][j]);
            }
        }
        __syncthreads();
    }

    // epilogue: alpha dots + bf16 store
    float av[8], dv[8];
#pragma unroll
    for (int j = 0; j < 8; j++) { av[j] = asrc[tx * 8 + j]; dv[j] = adst[tx * 8 + j]; }
#pragma unroll
    for (int i = 0; i < RPT; i++) {
        float ps = 0.f, pd = 0.f;
#pragma unroll
        for (int j = 0; j < 8; j++) {
            ps = fmaf(acc[i][j], av[j], ps);
            pd = fmaf(acc[i][j], dv[j], pd);
        }
        ps += __shfl_xor(ps, 1); pd += __shfl_xor(pd, 1);
        if constexpr (TPH == 4) { ps += __shfl_xor(ps, 2); pd += __shfl_xor(pd, 2); }
        int gr = row0 + ty * RPT + i;
        if (gr < M) {
            if ((tx % TPH) == 0) {
                As[gr * 4 + tx / TPH] = ps;
                Ad[gr * 4 + tx / TPH] = pd;
            }
            us8 o;
#pragma unroll
            for (int j = 0; j < 8; j++) o.v[j] = f2b(acc[i][j]);
            *(us8*)&Y[(size_t)gr * NCOL + tx * 8] = o;
        }
    }
}

// ------- aggregation: one wave per dst node, 2 edges per iteration, bf16 gather -------
// out[i] = ( sum_{e:dst=i} exp(leaky(As[src]+Ad[i])) * h[src] ) / sum exp(...)
// (segment-max dropped: softmax ratio invariant; |e| small -> fp32-safe)

template<bool RELU>
__global__ void agg128_k(const unsigned short* __restrict__ Hb,
                         const float* __restrict__ As, const float* __restrict__ Ad,
                         const int* __restrict__ offs, const int* __restrict__ csr,
                         const float* __restrict__ bias,
                         unsigned short* __restrict__ Outb, int n) {
    int wid  = (blockIdx.x * blockDim.x + threadIdx.x) >> 6;
    int lane = threadIdx.x & 63;
    if (wid >= n) return;
    const int q = lane & 31, half = lane >> 5;
    const int head = q >> 3, c0 = q * 4;   // channels 4q..4q+3, head = 4q/32
    int beg = offs[wid], end = offs[wid + 1];
    float ad = Ad[wid * 4 + head];
    float a0 = 0.f, a1 = 0.f, a2 = 0.f, a3 = 0.f, sw = 0.f;
    for (int e = beg; e < end; e += 2) {
        int ee = e + half;
        int s = csr[ee < end ? ee : end - 1];
        float ev = As[s * 4 + head] + ad;
        ev = ev > 0.f ? ev : 0.2f * ev;
        float w = (ee < end) ? __expf(ev) : 0.f;
        sw += w;
        ushort4 hv = *(const ushort4*)&Hb[(size_t)s * 128 + c0];
        a0 = fmaf(w, b2f(hv.x), a0);
        a1 = fmaf(w, b2f(hv.y), a1);
        a2 = fmaf(w, b2f(hv.z), a2);
        a3 = fmaf(w, b2f(hv.w), a3);
    }
    sw += __shfl_xor(sw, 32);
    a0 += __shfl_xor(a0, 32); a1 += __shfl_xor(a1, 32);
    a2 += __shfl_xor(a2, 32); a3 += __shfl_xor(a3, 32);
    if (half == 0) {
        float inv = 1.f / sw;
        float o0 = fmaf(a0, inv, bias[c0]);
        float o1 = fmaf(a1, inv, bias[c0 + 1]);
        float o2 = fmaf(a2, inv, bias[c0 + 2]);
        float o3 = fmaf(a3, inv, bias[c0 + 3]);
        if (RELU) {
            o0 = fmaxf(o0, 0.f); o1 = fmaxf(o1, 0.f);
            o2 = fmaxf(o2, 0.f); o3 = fmaxf(o3, 0.f);
        }
        ushort4 o; o.x = f2b(o0); o.y = f2b(o1); o.z = f2b(o2); o.w = f2b(o3);
        *(ushort4*)&Outb[(size_t)wid * 128 + c0] = o;
    }
}

__global__ void agg64_k(const unsigned short* __restrict__ Hb,
                        const float* __restrict__ As, const float* __restrict__ Ad,
                        const int* __restrict__ offs, const int* __restrict__ csr,
                        const float* __restrict__ bias,
                        float* __restrict__ Out, int n) {
    int wid  = (blockIdx.x * blockDim.x + threadIdx.x) >> 6;
    int lane = threadIdx.x & 63;
    if (wid >= n) return;
    const int q = lane & 31, half = lane >> 5;
    const int head = q >> 3, c0 = q * 2;   // channels 2q..2q+1, head = 2q/16
    int beg = offs[wid], end = offs[wid + 1];
    float ad = Ad[wid * 4 + head];
    float a0 = 0.f, a1 = 0.f, sw = 0.f;
    for (int e = beg; e < end; e += 2) {
        int ee = e + half;
        int s = csr[ee < end ? ee : end - 1];
        float ev = As[s * 4 + head] + ad;
        ev = ev > 0.f ? ev : 0.2f * ev;
        float w = (ee < end) ? __expf(ev) : 0.f;
        sw += w;
        ushort2 hv = *(const ushort2*)&Hb[(size_t)s * 64 + c0];
        a0 = fmaf(w, b2f(hv.x), a0);
        a1 = fmaf(w, b2f(hv.y), a1);
    }
    sw += __shfl_xor(sw, 32);
    a0 += __shfl_xor(a0, 32); a1 += __shfl_xor(a1, 32);
    if (half == 0) {
        float inv = 1.f / sw;
        float2 o;
        o.x = fmaf(a0, inv, bias[c0]);
        o.y = fmaf(a1, inv, bias[c0 + 1]);
        *(float2*)&Out[(size_t)wid * 64 + c0] = o;
    }
}

// ---------------- global add pool + FC ----------------

__global__ void pool_k(const float* __restrict__ h2, float* __restrict__ g, int n) {
    __shared__ float ls[256];
    int c   = threadIdx.x & 63;
    int rg  = (blockIdx.x * blockDim.x + threadIdx.x) >> 6;
    int nrg = (gridDim.x * blockDim.x) >> 6;
    float acc = 0.f;
    for (int r = rg; r < n; r += nrg) acc += h2[(size_t)r * 64 + c];
    ls[threadIdx.x] = acc;
    __syncthreads();
    if (threadIdx.x < 64) {
        float v = ls[threadIdx.x] + ls[threadIdx.x + 64] +
                  ls[threadIdx.x + 128] + ls[threadIdx.x + 192];
        atomicAdd(&g[c], v);
    }
}

__global__ void fc_k(const float* __restrict__ g, const float* __restrict__ w,
                     const float* __restrict__ b, float* __restrict__ out) {
    int j = threadIdx.x;
    if (j < 2) {
        float acc = b[j];
        for (int c = 0; c < 64; c++) acc = fmaf(g[c], w[c * 2 + j], acc);
        out[j] = acc;
    }
}

// ---------------- launch ----------------

static inline size_t align256(size_t x) { return (x + 255) & ~(size_t)255; }

extern "C" void kernel_launch(void* const* d_in, const int* in_sizes, int n_in,
                              void* d_out, int out_size, void* d_ws, size_t ws_size,
                              hipStream_t stream) {
    const float* x     = (const float*)d_in[0];
    const int*   ei    = (const int*)  d_in[1];
    const float* W1    = (const float*)d_in[2];
    const float* asrc1 = (const float*)d_in[3];
    const float* adst1 = (const float*)d_in[4];
    const float* b1    = (const float*)d_in[5];
    const float* W2    = (const float*)d_in[6];
    const float* asrc2 = (const float*)d_in[7];
    const float* adst2 = (const float*)d_in[8];
    const float* b2    = (const float*)d_in[9];
    const float* fcw   = (const float*)d_in[10];
    const float* fcb   = (const float*)d_in[11];
    float* out = (float*)d_out;

    const int N = in_sizes[0] / 128;
    const int E = in_sizes[1] / 2;
    const int TOT = E + N;

    // workspace carve-up
    char* w = (char*)d_ws;
    size_t off = 0;
    int* deg  = (int*)(w + off); off = align256(off + (size_t)N * 4);
    int* fill = (int*)(w + off); off = align256(off + (size_t)N * 4);
    int* offs = (int*)(w + off); off = align256(off + (size_t)(N + 1) * 4);
    int* bsum = (int*)(w + off); off = align256(off + 256 * 4);
    int* csr  = (int*)(w + off); off = align256(off + (size_t)TOT * 4);
    float* As = (float*)(w + off); off = align256(off + (size_t)N * 4 * 4);
    float* Ad = (float*)(w + off); off = align256(off + (size_t)N * 4 * 4);
    float* g  = (float*)(w + off); off = align256(off + 66 * 4);
    unsigned short* bufH = (unsigned short*)(w + off); off = align256(off + (size_t)N * 128 * 2);
    unsigned short* bufO = (unsigned short*)(w + off); off = align256(off + (size_t)N * 128 * 4);
    float* out2 = (float*)bufO;   // layer-2 output aliases bufO (fp32, N x 64)

    const int nb = (N + 1023) / 1024;

    // --- build CSR (by dst, self loops included) ---
    init_k<<<(N + 255) / 256, 256, 0, stream>>>(deg, fill, g, N);
    hist_k<<<(E + 255) / 256, 256, 0, stream>>>(ei, deg, E);
    scan_block_k<<<nb, 1024, 0, stream>>>(deg, offs, bsum, N);
    scan_tops_k<<<1, 128, 0, stream>>>(bsum, nb);
    scan_add_k<<<(N + 255) / 256, 256, 0, stream>>>(offs, bsum, N, TOT);
    scatter_k<<<(TOT + 255) / 256, 256, 0, stream>>>(ei, fill, offs, csr, E, N);

    // --- layer 1 ---
    gemm_alpha_k<128, false><<<(N + 63) / 64, 256, 0, stream>>>(
        x, W1, asrc1, adst1, bufH, As, Ad, N);
    agg128_k<true><<<(N * 64 + 255) / 256, 256, 0, stream>>>(
        bufH, As, Ad, offs, csr, b1, bufO, N);

    // --- layer 2 ---
    gemm_alpha_k<64, true><<<(N + 63) / 64, 256, 0, stream>>>(
        bufO, W2, asrc2, adst2, bufH, As, Ad, N);
    agg64_k<<<(N * 64 + 255) / 256, 256, 0, stream>>>(
        bufH, As, Ad, offs, csr, b2, out2, N);

    // --- pool + fc ---
    pool_k<<<256, 256, 0, stream>>>(out2, g, N);
    fc_k<<<1, 64, 0, stream>>>(g, fcw, fcb, out);
}

// Round 4
// 476.471 us; speedup vs baseline: 1.5159x; 1.2304x over previous
//
#include <hip/hip_runtime.h>
#include <hip/hip_bf16.h>
#include <math.h>

// ---------------- bf16 helpers ----------------

__device__ __forceinline__ float b2f(unsigned short u) {
    return __uint_as_float(((unsigned)u) << 16);
}
__device__ __forceinline__ unsigned short f2b(float f) {
    unsigned x = __float_as_uint(f);
    return (unsigned short)((x + 0x7fffu + ((x >> 16) & 1u)) >> 16);  // RNE
}

struct alignas(16) us8 { unsigned short v[8]; };

// ---------------- CSR build ----------------

__global__ void init_k(int* __restrict__ deg, int* __restrict__ fill,
                       float* __restrict__ g, int n) {
    int i = blockIdx.x * blockDim.x + threadIdx.x;
    if (i < n) { deg[i] = 1; fill[i] = 0; }   // deg starts at 1: self loop
    if (i < 66) g[i] = 0.f;
}

__global__ void hist_k(const int* __restrict__ ei, int* __restrict__ deg, int E) {
    int i = blockIdx.x * blockDim.x + threadIdx.x;
    if (i < E) atomicAdd(&deg[ei[E + i]], 1);   // dst row of edge_index
}

__global__ void scan_block_k(const int* __restrict__ deg, int* __restrict__ offs,
                             int* __restrict__ bsum, int n) {
    __shared__ int ls[1024];
    int t = threadIdx.x;
    int i = blockIdx.x * 1024 + t;
    int v = (i < n) ? deg[i] : 0;
    ls[t] = v;
    __syncthreads();
    for (int off = 1; off < 1024; off <<= 1) {
        int add = (t >= off) ? ls[t - off] : 0;
        __syncthreads();
        ls[t] += add;
        __syncthreads();
    }
    if (i < n) offs[i] = ls[t] - v;          // exclusive scan (partial)
    if (t == 1023) bsum[blockIdx.x] = ls[1023];
}

__global__ void scan_tops_k(int* __restrict__ bsum, int nb) {
    __shared__ int ls[128];
    int t = threadIdx.x;
    int v = (t < nb) ? bsum[t] : 0;
    ls[t] = v;
    __syncthreads();
    for (int off = 1; off < 128; off <<= 1) {
        int add = (t >= off) ? ls[t - off] : 0;
        __syncthreads();
        ls[t] += add;
        __syncthreads();
    }
    if (t < nb) bsum[t] = ls[t] - v;         // exclusive block offsets
}

__global__ void scan_add_k(int* __restrict__ offs, const int* __restrict__ bsum,
                           int n, int total) {
    int i = blockIdx.x * blockDim.x + threadIdx.x;
    if (i < n) offs[i] += bsum[i >> 10];
    if (i == 0) offs[n] = total;
}

__global__ void scatter_k(const int* __restrict__ ei, int* __restrict__ fill,
                          const int* __restrict__ offs, int* __restrict__ csr,
                          int E, int n) {
    int i = blockIdx.x * blockDim.x + threadIdx.x;
    int total = E + n;
    if (i >= total) return;
    int s, d;
    if (i < E) { s = ei[i]; d = ei[E + i]; }
    else       { s = d = i - E; }            // self loop
    int pos = offs[d] + atomicAdd(&fill[d], 1);
    csr[pos] = s;
}

// ------- GEMM: Y[M,NCOL](bf16) = X[M,128] @ W[128,NCOL], fused alpha dots -------
// alpha_src[r][h] = sum_c Y[r][h*C+c]*asrc[h*C+c]  computed from fp32 acc in epilogue.

template<int NCOL, bool XBF16>
__global__ __launch_bounds__(256) void gemm_alpha_k(
        const void* __restrict__ Xv, const float* __restrict__ W,
        const float* __restrict__ asrc, const float* __restrict__ adst,
        unsigned short* __restrict__ Y, float* __restrict__ As,
        float* __restrict__ Ad, int M) {
    constexpr int TX  = NCOL / 8;        // 16 or 8
    constexpr int TY  = 256 / TX;        // 16 or 32
    constexpr int RPT = 64 / TY;         // 4 or 2 rows per thread
    constexpr int TPH = (NCOL == 128) ? 4 : 2;  // threads covering one head's channels
    __shared__ float xs[64][65];
    __shared__ float ws[64][NCOL];
    const int t    = threadIdx.x;
    const int row0 = blockIdx.x * 64;
    const int tx   = t % TX, ty = t / TX;
    float acc[RPT][8];
#pragma unroll
    for (int i = 0; i < RPT; i++)
#pragma unroll
        for (int j = 0; j < 8; j++) acc[i][j] = 0.f;

    for (int kb = 0; kb < 128; kb += 64) {
        for (int idx = t; idx < 64 * NCOL; idx += 256) {
            int kk = idx / NCOL, c = idx % NCOL;
            ws[kk][c] = W[(size_t)(kb + kk) * NCOL + c];
        }
        if constexpr (XBF16) {
            const unsigned short* Xb = (const unsigned short*)Xv;
            for (int idx = t; idx < 64 * 32; idx += 256) {
                int r = idx >> 5, k2 = (idx & 31) * 2;
                int gr = row0 + r;
                float v0 = 0.f, v1 = 0.f;
                if (gr < M) {
                    ushort2 u = *(const ushort2*)&Xb[(size_t)gr * 128 + kb + k2];
                    v0 = b2f(u.x); v1 = b2f(u.y);
                }
                xs[r][k2] = v0; xs[r][k2 + 1] = v1;
            }
        } else {
            const float* X = (const float*)Xv;
            for (int idx = t; idx < 64 * 64; idx += 256) {
                int r = idx >> 6, kk = idx & 63;
                int gr = row0 + r;
                xs[r][kk] = (gr < M) ? X[(size_t)gr * 128 + kb + kk] : 0.f;
            }
        }
        __syncthreads();
#pragma unroll 8
        for (int kk = 0; kk < 64; kk++) {
            float wv[8];
#pragma unroll
            for (int j = 0; j < 8; j++) wv[j] = ws[kk][tx * 8 + j];
#pragma unroll
            for (int i = 0; i < RPT; i++) {
                float xv = xs[ty * RPT + i][kk];
#pragma unroll
                for (int j = 0; j < 8; j++) acc[i][j] = fmaf(xv, wv[j], acc[i][j]);
            }
        }
        __syncthreads();
    }

    // epilogue: alpha dots + bf16 store
    float av[8], dv[8];
#pragma unroll
    for (int j = 0; j < 8; j++) { av[j] = asrc[tx * 8 + j]; dv[j] = adst[tx * 8 + j]; }
#pragma unroll
    for (int i = 0; i < RPT; i++) {
        float ps = 0.f, pd = 0.f;
#pragma unroll
        for (int j = 0; j < 8; j++) {
            ps = fmaf(acc[i][j], av[j], ps);
            pd = fmaf(acc[i][j], dv[j], pd);
        }
        ps += __shfl_xor(ps, 1); pd += __shfl_xor(pd, 1);
        if constexpr (TPH == 4) { ps += __shfl_xor(ps, 2); pd += __shfl_xor(pd, 2); }
        int gr = row0 + ty * RPT + i;
        if (gr < M) {
            if ((tx % TPH) == 0) {
                As[gr * 4 + tx / TPH] = ps;
                Ad[gr * 4 + tx / TPH] = pd;
            }
            us8 o;
#pragma unroll
            for (int j = 0; j < 8; j++) o.v[j] = f2b(acc[i][j]);
            *(us8*)&Y[(size_t)gr * NCOL + tx * 8] = o;
        }
    }
}

// ------- aggregation: one wave per dst node ----------------------------------
// out[i] = ( sum_{e:dst=i} exp(leaky(As[src]+Ad[i])) * h[src] ) / sum exp(...)
// (segment-max dropped: softmax ratio invariant; |e| small -> fp32-safe)
// v3: preload up to 64 edge indices into registers (1 coalesced load), then
// broadcast via shfl -> only ONE dependent memory level (As/H gathers, which
// issue in parallel). 4 edges in flight per iter (16 lanes/edge, ushort8 each:
// the 256B H row is one fully-coalesced request).

template<bool RELU>
__global__ void agg128_k(const unsigned short* __restrict__ Hb,
                         const float* __restrict__ As, const float* __restrict__ Ad,
                         const int* __restrict__ offs, const int* __restrict__ csr,
                         const float* __restrict__ bias,
                         unsigned short* __restrict__ Outb, int n) {
    int wid  = (blockIdx.x * blockDim.x + threadIdx.x) >> 6;
    int lane = threadIdx.x & 63;
    if (wid >= n) return;
    const int g = lane >> 4;          // edge slot within iteration (0..3)
    const int q = lane & 15;          // channel octet: channels 8q..8q+7
    const int head = q >> 2;
    const int beg = offs[wid], end = offs[wid + 1];
    const float ad = Ad[wid * 4 + head];
    float acc[8];
#pragma unroll
    for (int k = 0; k < 8; k++) acc[k] = 0.f;
    float sw = 0.f;

    for (int cb = beg; cb < end; cb += 64) {
        const int nc = min(64, end - cb);
        const int sreg = csr[cb + (lane < nc ? lane : 0)];   // 1 coalesced load
        const int ncr = (nc + 3) & ~3;                        // keep lanes convergent
        for (int j = g; j < ncr; j += 4) {
            const bool valid = j < nc;
            const int s = __shfl(sreg, valid ? j : 0);
            float ev = As[s * 4 + head] + ad;
            ev = ev > 0.f ? ev : 0.2f * ev;
            const float w = valid ? __expf(ev) : 0.f;
            const us8 hv = *(const us8*)&Hb[(size_t)s * 128 + q * 8];
            sw += w;
#pragma unroll
            for (int k = 0; k < 8; k++) acc[k] = fmaf(w, b2f(hv.v[k]), acc[k]);
        }
    }

    sw += __shfl_xor(sw, 16); sw += __shfl_xor(sw, 32);
#pragma unroll
    for (int k = 0; k < 8; k++) {
        acc[k] += __shfl_xor(acc[k], 16);
        acc[k] += __shfl_xor(acc[k], 32);
    }
    if (g == 0) {
        const float inv = 1.f / sw;
        us8 o;
#pragma unroll
        for (int k = 0; k < 8; k++) {
            float v = fmaf(acc[k], inv, bias[q * 8 + k]);
            if (RELU) v = fmaxf(v, 0.f);
            o.v[k] = f2b(v);
        }
        *(us8*)&Outb[(size_t)wid * 128 + q * 8] = o;
    }
}

// 8 edges in flight per iter (8 lanes/edge, ushort8 each: 128B row, coalesced)

__global__ void agg64_k(const unsigned short* __restrict__ Hb,
                        const float* __restrict__ As, const float* __restrict__ Ad,
                        const int* __restrict__ offs, const int* __restrict__ csr,
                        const float* __restrict__ bias,
                        float* __restrict__ Out, int n) {
    int wid  = (blockIdx.x * blockDim.x + threadIdx.x) >> 6;
    int lane = threadIdx.x & 63;
    if (wid >= n) return;
    const int g = lane >> 3;          // edge slot within iteration (0..7)
    const int q = lane & 7;           // channel octet: channels 8q..8q+7
    const int head = q >> 1;
    const int beg = offs[wid], end = offs[wid + 1];
    const float ad = Ad[wid * 4 + head];
    float acc[8];
#pragma unroll
    for (int k = 0; k < 8; k++) acc[k] = 0.f;
    float sw = 0.f;

    for (int cb = beg; cb < end; cb += 64) {
        const int nc = min(64, end - cb);
        const int sreg = csr[cb + (lane < nc ? lane : 0)];
        const int ncr = (nc + 7) & ~7;
        for (int j = g; j < ncr; j += 8) {
            const bool valid = j < nc;
            const int s = __shfl(sreg, valid ? j : 0);
            float ev = As[s * 4 + head] + ad;
            ev = ev > 0.f ? ev : 0.2f * ev;
            const float w = valid ? __expf(ev) : 0.f;
            const us8 hv = *(const us8*)&Hb[(size_t)s * 64 + q * 8];
            sw += w;
#pragma unroll
            for (int k = 0; k < 8; k++) acc[k] = fmaf(w, b2f(hv.v[k]), acc[k]);
        }
    }

    sw += __shfl_xor(sw, 8); sw += __shfl_xor(sw, 16); sw += __shfl_xor(sw, 32);
#pragma unroll
    for (int k = 0; k < 8; k++) {
        acc[k] += __shfl_xor(acc[k], 8);
        acc[k] += __shfl_xor(acc[k], 16);
        acc[k] += __shfl_xor(acc[k], 32);
    }
    if (g == 0) {
        const float inv = 1.f / sw;
        float4 o0, o1;
        o0.x = fmaf(acc[0], inv, bias[q * 8 + 0]);
        o0.y = fmaf(acc[1], inv, bias[q * 8 + 1]);
        o0.z = fmaf(acc[2], inv, bias[q * 8 + 2]);
        o0.w = fmaf(acc[3], inv, bias[q * 8 + 3]);
        o1.x = fmaf(acc[4], inv, bias[q * 8 + 4]);
        o1.y = fmaf(acc[5], inv, bias[q * 8 + 5]);
        o1.z = fmaf(acc[6], inv, bias[q * 8 + 6]);
        o1.w = fmaf(acc[7], inv, bias[q * 8 + 7]);
        *(float4*)&Out[(size_t)wid * 64 + q * 8]     = o0;
        *(float4*)&Out[(size_t)wid * 64 + q * 8 + 4] = o1;
    }
}

// ---------------- global add pool + FC ----------------

__global__ void pool_k(const float* __restrict__ h2, float* __restrict__ g, int n) {
    __shared__ float ls[256];
    int c   = threadIdx.x & 63;
    int rg  = (blockIdx.x * blockDim.x + threadIdx.x) >> 6;
    int nrg = (gridDim.x * blockDim.x) >> 6;
    float acc = 0.f;
    for (int r = rg; r < n; r += nrg) acc += h2[(size_t)r * 64 + c];
    ls[threadIdx.x] = acc;
    __syncthreads();
    if (threadIdx.x < 64) {
        float v = ls[threadIdx.x] + ls[threadIdx.x + 64] +
                  ls[threadIdx.x + 128] + ls[threadIdx.x + 192];
        atomicAdd(&g[c], v);
    }
}

__global__ void fc_k(const float* __restrict__ g, const float* __restrict__ w,
                     const float* __restrict__ b, float* __restrict__ out) {
    int j = threadIdx.x;
    if (j < 2) {
        float acc = b[j];
        for (int c = 0; c < 64; c++) acc = fmaf(g[c], w[c * 2 + j], acc);
        out[j] = acc;
    }
}

// ---------------- launch ----------------

static inline size_t align256(size_t x) { return (x + 255) & ~(size_t)255; }

extern "C" void kernel_launch(void* const* d_in, const int* in_sizes, int n_in,
                              void* d_out, int out_size, void* d_ws, size_t ws_size,
                              hipStream_t stream) {
    const float* x     = (const float*)d_in[0];
    const int*   ei    = (const int*)  d_in[1];
    const float* W1    = (const float*)d_in[2];
    const float* asrc1 = (const float*)d_in[3];
    const float* adst1 = (const float*)d_in[4];
    const float* b1    = (const float*)d_in[5];
    const float* W2    = (const float*)d_in[6];
    const float* asrc2 = (const float*)d_in[7];
    const float* adst2 = (const float*)d_in[8];
    const float* b2    = (const float*)d_in[9];
    const float* fcw   = (const float*)d_in[10];
    const float* fcb   = (const float*)d_in[11];
    float* out = (float*)d_out;

    const int N = in_sizes[0] / 128;
    const int E = in_sizes[1] / 2;
    const int TOT = E + N;

    // workspace carve-up
    char* w = (char*)d_ws;
    size_t off = 0;
    int* deg  = (int*)(w + off); off = align256(off + (size_t)N * 4);
    int* fill = (int*)(w + off); off = align256(off + (size_t)N * 4);
    int* offs = (int*)(w + off); off = align256(off + (size_t)(N + 1) * 4);
    int* bsum = (int*)(w + off); off = align256(off + 256 * 4);
    int* csr  = (int*)(w + off); off = align256(off + (size_t)TOT * 4);
    float* As = (float*)(w + off); off = align256(off + (size_t)N * 4 * 4);
    float* Ad = (float*)(w + off); off = align256(off + (size_t)N * 4 * 4);
    float* g  = (float*)(w + off); off = align256(off + 66 * 4);
    unsigned short* bufH = (unsigned short*)(w + off); off = align256(off + (size_t)N * 128 * 2);
    unsigned short* bufO = (unsigned short*)(w + off); off = align256(off + (size_t)N * 128 * 4);
    float* out2 = (float*)bufO;   // layer-2 output aliases bufO (fp32, N x 64)

    const int nb = (N + 1023) / 1024;

    // --- build CSR (by dst, self loops included) ---
    init_k<<<(N + 255) / 256, 256, 0, stream>>>(deg, fill, g, N);
    hist_k<<<(E + 255) / 256, 256, 0, stream>>>(ei, deg, E);
    scan_block_k<<<nb, 1024, 0, stream>>>(deg, offs, bsum, N);
    scan_tops_k<<<1, 128, 0, stream>>>(bsum, nb);
    scan_add_k<<<(N + 255) / 256, 256, 0, stream>>>(offs, bsum, N, TOT);
    scatter_k<<<(TOT + 255) / 256, 256, 0, stream>>>(ei, fill, offs, csr, E, N);

    // --- layer 1 ---
    gemm_alpha_k<128, false><<<(N + 63) / 64, 256, 0, stream>>>(
        x, W1, asrc1, adst1, bufH, As, Ad, N);
    agg128_k<true><<<(N * 64 + 255) / 256, 256, 0, stream>>>(
        bufH, As, Ad, offs, csr, b1, bufO, N);

    // --- layer 2 ---
    gemm_alpha_k<64, true><<<(N + 63) / 64, 256, 0, stream>>>(
        bufO, W2, asrc2, adst2, bufH, As, Ad, N);
    agg64_k<<<(N * 64 + 255) / 256, 256, 0, stream>>>(
        bufH, As, Ad, offs, csr, b2, out2, N);

    // --- pool + fc ---
    pool_k<<<256, 256, 0, stream>>>(out2, g, N);
    fc_k<<<1, 64, 0, stream>>>(g, fcw, fcb, out);
}

// Round 5
// 366.054 us; speedup vs baseline: 1.9732x; 1.3016x over previous
//
#include <hip/hip_runtime.h>
#include <hip/hip_bf16.h>
#include <math.h>

// ---------------- bf16 helpers ----------------

__device__ __forceinline__ float b2f(unsigned short u) {
    return __uint_as_float(((unsigned)u) << 16);
}
__device__ __forceinline__ unsigned short f2b(float f) {
    unsigned x = __float_as_uint(f);
    return (unsigned short)((x + 0x7fffu + ((x >> 16) & 1u)) >> 16);  // RNE
}

struct alignas(16) us8 { unsigned short v[8]; };

// ================= CSR build v2: bucket-binned counting sort =================
// Items 0..E-1 are edges (src=ei[i], dst=ei[E+i]); items E..E+N-1 are self loops.
// Bucket b = dst >> 8 (256 nodes / bucket). All per-node atomics live in LDS;
// csr writes are confined to one bucket's ~70KB window per block (single XCD,
// lines fully populated before writeback).

__global__ void init_k(int* __restrict__ bucketCnt, float* __restrict__ g) {
    int i = threadIdx.x;
    if (i < 512) bucketCnt[i] = 0;
    if (i < 66)  g[i] = 0.f;
}

__global__ void bucket_hist_k(const int* __restrict__ ei, int* __restrict__ bucketCnt,
                              int E, int N, int NB) {
    __shared__ int cnt[512];
    for (int t = threadIdx.x; t < 512; t += blockDim.x) cnt[t] = 0;
    __syncthreads();
    const int ITEMS = E + N;
    for (int i = blockIdx.x * blockDim.x + threadIdx.x; i < ITEMS;
         i += gridDim.x * blockDim.x) {
        int d = (i < E) ? ei[E + i] : (i - E);
        atomicAdd(&cnt[d >> 8], 1);
    }
    __syncthreads();
    for (int t = threadIdx.x; t < NB; t += blockDim.x)
        if (cnt[t]) atomicAdd(&bucketCnt[t], cnt[t]);
}

__global__ void bucket_scan_k(const int* __restrict__ bucketCnt,
                              int* __restrict__ bucketOff,
                              int* __restrict__ bucketFill, int NB) {
    __shared__ int ls[512];
    int t = threadIdx.x;
    int v = (t < NB) ? bucketCnt[t] : 0;
    ls[t] = v;
    __syncthreads();
    for (int off = 1; off < 512; off <<= 1) {
        int a = (t >= off) ? ls[t - off] : 0;
        __syncthreads();
        ls[t] += a;
        __syncthreads();
    }
    if (t < NB) { int e = ls[t] - v; bucketOff[t] = e; bucketFill[t] = e; }
}

// partition items into buckets: LDS ranking + per-(block,bucket) chunk reservation
__global__ __launch_bounds__(256) void bin_scatter_k(const int* __restrict__ ei,
                                                     int* __restrict__ bucketFill,
                                                     int2* __restrict__ binned,
                                                     int E, int N) {
    __shared__ int cnt[512];
    __shared__ int base[512];
    const int ITEMS = E + N;
    const int t = threadIdx.x;
    const int chunk0 = blockIdx.x * 4096;
    for (int b = t; b < 512; b += 256) cnt[b] = 0;
    __syncthreads();
    int s[16], d[16], r[16];
#pragma unroll
    for (int j = 0; j < 16; j++) {
        int i = chunk0 + j * 256 + t;
        if (i < ITEMS) {
            if (i < E) { s[j] = ei[i]; d[j] = ei[E + i]; }
            else       { s[j] = d[j] = i - E; }
            r[j] = atomicAdd(&cnt[d[j] >> 8], 1);
        } else d[j] = -1;
    }
    __syncthreads();
    for (int b = t; b < 512; b += 256) {
        int c = cnt[b];
        base[b] = c ? atomicAdd(&bucketFill[b], c) : 0;
    }
    __syncthreads();
#pragma unroll
    for (int j = 0; j < 16; j++)
        if (d[j] >= 0) binned[base[d[j] >> 8] + r[j]] = make_int2(s[j], d[j]);
}

// per-bucket node-degree histogram (LDS counters), sequential deg write
__global__ void node_hist_k(const int2* __restrict__ binned,
                            const int* __restrict__ bucketOff,
                            const int* __restrict__ bucketCnt,
                            int* __restrict__ deg, int N) {
    __shared__ int cnt[256];
    const int b = blockIdx.x;
    cnt[threadIdx.x] = 0;
    __syncthreads();
    const int beg = bucketOff[b], c = bucketCnt[b];
    for (int i = threadIdx.x; i < c; i += 256) {
        int2 sd = binned[beg + i];
        atomicAdd(&cnt[sd.y & 255], 1);
    }
    __syncthreads();
    int node = b * 256 + threadIdx.x;
    if (node < N) deg[node] = cnt[threadIdx.x];
}

// ---------------- node-degree exclusive scan ----------------

__global__ void scan_block_k(const int* __restrict__ deg, int* __restrict__ offs,
                             int* __restrict__ bsum, int n) {
    __shared__ int ls[1024];
    int t = threadIdx.x;
    int i = blockIdx.x * 1024 + t;
    int v = (i < n) ? deg[i] : 0;
    ls[t] = v;
    __syncthreads();
    for (int off = 1; off < 1024; off <<= 1) {
        int add = (t >= off) ? ls[t - off] : 0;
        __syncthreads();
        ls[t] += add;
        __syncthreads();
    }
    if (i < n) offs[i] = ls[t] - v;          // exclusive scan (partial)
    if (t == 1023) bsum[blockIdx.x] = ls[1023];
}

__global__ void scan_tops_k(int* __restrict__ bsum, int nb) {
    __shared__ int ls[128];
    int t = threadIdx.x;
    int v = (t < nb) ? bsum[t] : 0;
    ls[t] = v;
    __syncthreads();
    for (int off = 1; off < 128; off <<= 1) {
        int add = (t >= off) ? ls[t - off] : 0;
        __syncthreads();
        ls[t] += add;
        __syncthreads();
    }
    if (t < nb) bsum[t] = ls[t] - v;         // exclusive block offsets
}

__global__ void scan_add_k(int* __restrict__ offs, const int* __restrict__ bsum,
                           int n, int total) {
    int i = blockIdx.x * blockDim.x + threadIdx.x;
    if (i < n) offs[i] += bsum[i >> 10];
    if (i == 0) offs[n] = total;
}

// per-bucket CSR scatter: LDS fill counters, writes confined to bucket window
__global__ void csr_scatter_k(const int2* __restrict__ binned,
                              const int* __restrict__ bucketOff,
                              const int* __restrict__ bucketCnt,
                              const int* __restrict__ offs, int* __restrict__ csr) {
    __shared__ int fill[256];
    const int b = blockIdx.x;
    fill[threadIdx.x] = 0;
    __syncthreads();
    const int beg = bucketOff[b], c = bucketCnt[b];
    for (int i = threadIdx.x; i < c; i += 256) {
        int2 sd = binned[beg + i];
        int r = atomicAdd(&fill[sd.y & 255], 1);
        csr[offs[sd.y] + r] = sd.x;
    }
}

// ------- GEMM: Y[M,NCOL](bf16) = X[M,128] @ W[128,NCOL], fused alpha dots -------
// alpha_src[r][h] = sum_c Y[r][h*C+c]*asrc[h*C+c]  computed from fp32 acc in epilogue.

template<int NCOL, bool XBF16>
__global__ __launch_bounds__(256) void gemm_alpha_k(
        const void* __restrict__ Xv, const float* __restrict__ W,
        const float* __restrict__ asrc, const float* __restrict__ adst,
        unsigned short* __restrict__ Y, float* __restrict__ As,
        float* __restrict__ Ad, int M) {
    constexpr int TX  = NCOL / 8;        // 16 or 8
    constexpr int TY  = 256 / TX;        // 16 or 32
    constexpr int RPT = 64 / TY;         // 4 or 2 rows per thread
    constexpr int TPH = (NCOL == 128) ? 4 : 2;  // threads covering one head's channels
    __shared__ float xs[64][65];
    __shared__ float ws[64][NCOL];
    const int t    = threadIdx.x;
    const int row0 = blockIdx.x * 64;
    const int tx   = t % TX, ty = t / TX;
    float acc[RPT][8];
#pragma unroll
    for (int i = 0; i < RPT; i++)
#pragma unroll
        for (int j = 0; j < 8; j++) acc[i][j] = 0.f;

    for (int kb = 0; kb < 128; kb += 64) {
        for (int idx = t; idx < 64 * NCOL; idx += 256) {
            int kk = idx / NCOL, c = idx % NCOL;
            ws[kk][c] = W[(size_t)(kb + kk) * NCOL + c];
        }
        if constexpr (XBF16) {
            const unsigned short* Xb = (const unsigned short*)Xv;
            for (int idx = t; idx < 64 * 32; idx += 256) {
                int r = idx >> 5, k2 = (idx & 31) * 2;
                int gr = row0 + r;
                float v0 = 0.f, v1 = 0.f;
                if (gr < M) {
                    ushort2 u = *(const ushort2*)&Xb[(size_t)gr * 128 + kb + k2];
                    v0 = b2f(u.x); v1 = b2f(u.y);
                }
                xs[r][k2] = v0; xs[r][k2 + 1] = v1;
            }
        } else {
            const float* X = (const float*)Xv;
            for (int idx = t; idx < 64 * 64; idx += 256) {
                int r = idx >> 6, kk = idx & 63;
                int gr = row0 + r;
                xs[r][kk] = (gr < M) ? X[(size_t)gr * 128 + kb + kk] : 0.f;
            }
        }
        __syncthreads();
#pragma unroll 8
        for (int kk = 0; kk < 64; kk++) {
            float wv[8];
#pragma unroll
            for (int j = 0; j < 8; j++) wv[j] = ws[kk][tx * 8 + j];
#pragma unroll
            for (int i = 0; i < RPT; i++) {
                float xv = xs[ty * RPT + i][kk];
#pragma unroll
                for (int j = 0; j < 8; j++) acc[i][j] = fmaf(xv, wv[j], acc[i][j]);
            }
        }
        __syncthreads();
    }

    // epilogue: alpha dots + bf16 store
    float av[8], dv[8];
#pragma unroll
    for (int j = 0; j < 8; j++) { av[j] = asrc[tx * 8 + j]; dv[j] = adst[tx * 8 + j]; }
#pragma unroll
    for (int i = 0; i < RPT; i++) {
        float ps = 0.f, pd = 0.f;
#pragma unroll
        for (int j = 0; j < 8; j++) {
            ps = fmaf(acc[i][j], av[j], ps);
            pd = fmaf(acc[i][j], dv[j], pd);
        }
        ps += __shfl_xor(ps, 1); pd += __shfl_xor(pd, 1);
        if constexpr (TPH == 4) { ps += __shfl_xor(ps, 2); pd += __shfl_xor(pd, 2); }
        int gr = row0 + ty * RPT + i;
        if (gr < M) {
            if ((tx % TPH) == 0) {
                As[gr * 4 + tx / TPH] = ps;
                Ad[gr * 4 + tx / TPH] = pd;
            }
            us8 o;
#pragma unroll
            for (int j = 0; j < 8; j++) o.v[j] = f2b(acc[i][j]);
            *(us8*)&Y[(size_t)gr * NCOL + tx * 8] = o;
        }
    }
}

// ------- aggregation: one wave per dst node ----------------------------------
// out[i] = ( sum_{e:dst=i} exp(leaky(As[src]+Ad[i])) * h[src] ) / sum exp(...)
// (segment-max dropped: softmax ratio invariant; |e| small -> fp32-safe)
// 64 edge indices preloaded per wave (1 coalesced load), broadcast via shfl;
// 4 edges in flight per iter (16 lanes/edge, us8 each: 256B row = 1 request).

template<bool RELU>
__global__ void agg128_k(const unsigned short* __restrict__ Hb,
                         const float* __restrict__ As, const float* __restrict__ Ad,
                         const int* __restrict__ offs, const int* __restrict__ csr,
                         const float* __restrict__ bias,
                         unsigned short* __restrict__ Outb, int n) {
    int wid  = (blockIdx.x * blockDim.x + threadIdx.x) >> 6;
    int lane = threadIdx.x & 63;
    if (wid >= n) return;
    const int g = lane >> 4;          // edge slot within iteration (0..3)
    const int q = lane & 15;          // channel octet: channels 8q..8q+7
    const int head = q >> 2;
    const int beg = offs[wid], end = offs[wid + 1];
    const float ad = Ad[wid * 4 + head];
    float acc[8];
#pragma unroll
    for (int k = 0; k < 8; k++) acc[k] = 0.f;
    float sw = 0.f;

    for (int cb = beg; cb < end; cb += 64) {
        const int nc = min(64, end - cb);
        const int sreg = csr[cb + (lane < nc ? lane : 0)];   // 1 coalesced load
        const int ncr = (nc + 3) & ~3;                        // keep lanes convergent
        for (int j = g; j < ncr; j += 4) {
            const bool valid = j < nc;
            const int s = __shfl(sreg, valid ? j : 0);
            float ev = As[s * 4 + head] + ad;
            ev = ev > 0.f ? ev : 0.2f * ev;
            const float w = valid ? __expf(ev) : 0.f;
            const us8 hv = *(const us8*)&Hb[(size_t)s * 128 + q * 8];
            sw += w;
#pragma unroll
            for (int k = 0; k < 8; k++) acc[k] = fmaf(w, b2f(hv.v[k]), acc[k]);
        }
    }

    sw += __shfl_xor(sw, 16); sw += __shfl_xor(sw, 32);
#pragma unroll
    for (int k = 0; k < 8; k++) {
        acc[k] += __shfl_xor(acc[k], 16);
        acc[k] += __shfl_xor(acc[k], 32);
    }
    if (g == 0) {
        const float inv = 1.f / sw;
        us8 o;
#pragma unroll
        for (int k = 0; k < 8; k++) {
            float v = fmaf(acc[k], inv, bias[q * 8 + k]);
            if (RELU) v = fmaxf(v, 0.f);
            o.v[k] = f2b(v);
        }
        *(us8*)&Outb[(size_t)wid * 128 + q * 8] = o;
    }
}

// 8 edges in flight per iter (8 lanes/edge, us8 each: 128B row, coalesced)

__global__ void agg64_k(const unsigned short* __restrict__ Hb,
                        const float* __restrict__ As, const float* __restrict__ Ad,
                        const int* __restrict__ offs, const int* __restrict__ csr,
                        const float* __restrict__ bias,
                        float* __restrict__ Out, int n) {
    int wid  = (blockIdx.x * blockDim.x + threadIdx.x) >> 6;
    int lane = threadIdx.x & 63;
    if (wid >= n) return;
    const int g = lane >> 3;          // edge slot within iteration (0..7)
    const int q = lane & 7;           // channel octet: channels 8q..8q+7
    const int head = q >> 1;
    const int beg = offs[wid], end = offs[wid + 1];
    const float ad = Ad[wid * 4 + head];
    float acc[8];
#pragma unroll
    for (int k = 0; k < 8; k++) acc[k] = 0.f;
    float sw = 0.f;

    for (int cb = beg; cb < end; cb += 64) {
        const int nc = min(64, end - cb);
        const int sreg = csr[cb + (lane < nc ? lane : 0)];
        const int ncr = (nc + 7) & ~7;
        for (int j = g; j < ncr; j += 8) {
            const bool valid = j < nc;
            const int s = __shfl(sreg, valid ? j : 0);
            float ev = As[s * 4 + head] + ad;
            ev = ev > 0.f ? ev : 0.2f * ev;
            const float w = valid ? __expf(ev) : 0.f;
            const us8 hv = *(const us8*)&Hb[(size_t)s * 64 + q * 8];
            sw += w;
#pragma unroll
            for (int k = 0; k < 8; k++) acc[k] = fmaf(w, b2f(hv.v[k]), acc[k]);
        }
    }

    sw += __shfl_xor(sw, 8); sw += __shfl_xor(sw, 16); sw += __shfl_xor(sw, 32);
#pragma unroll
    for (int k = 0; k < 8; k++) {
        acc[k] += __shfl_xor(acc[k], 8);
        acc[k] += __shfl_xor(acc[k], 16);
        acc[k] += __shfl_xor(acc[k], 32);
    }
    if (g == 0) {
        const float inv = 1.f / sw;
        float4 o0, o1;
        o0.x = fmaf(acc[0], inv, bias[q * 8 + 0]);
        o0.y = fmaf(acc[1], inv, bias[q * 8 + 1]);
        o0.z = fmaf(acc[2], inv, bias[q * 8 + 2]);
        o0.w = fmaf(acc[3], inv, bias[q * 8 + 3]);
        o1.x = fmaf(acc[4], inv, bias[q * 8 + 4]);
        o1.y = fmaf(acc[5], inv, bias[q * 8 + 5]);
        o1.z = fmaf(acc[6], inv, bias[q * 8 + 6]);
        o1.w = fmaf(acc[7], inv, bias[q * 8 + 7]);
        *(float4*)&Out[(size_t)wid * 64 + q * 8]     = o0;
        *(float4*)&Out[(size_t)wid * 64 + q * 8 + 4] = o1;
    }
}

// ---------------- global add pool + FC ----------------

__global__ void pool_k(const float* __restrict__ h2, float* __restrict__ g, int n) {
    __shared__ float ls[256];
    int c   = threadIdx.x & 63;
    int rg  = (blockIdx.x * blockDim.x + threadIdx.x) >> 6;
    int nrg = (gridDim.x * blockDim.x) >> 6;
    float acc = 0.f;
    for (int r = rg; r < n; r += nrg) acc += h2[(size_t)r * 64 + c];
    ls[threadIdx.x] = acc;
    __syncthreads();
    if (threadIdx.x < 64) {
        float v = ls[threadIdx.x] + ls[threadIdx.x + 64] +
                  ls[threadIdx.x + 128] + ls[threadIdx.x + 192];
        atomicAdd(&g[c], v);
    }
}

__global__ void fc_k(const float* __restrict__ g, const float* __restrict__ w,
                     const float* __restrict__ b, float* __restrict__ out) {
    int j = threadIdx.x;
    if (j < 2) {
        float acc = b[j];
        for (int c = 0; c < 64; c++) acc = fmaf(g[c], w[c * 2 + j], acc);
        out[j] = acc;
    }
}

// ---------------- launch ----------------

static inline size_t align256(size_t x) { return (x + 255) & ~(size_t)255; }

extern "C" void kernel_launch(void* const* d_in, const int* in_sizes, int n_in,
                              void* d_out, int out_size, void* d_ws, size_t ws_size,
                              hipStream_t stream) {
    const float* x     = (const float*)d_in[0];
    const int*   ei    = (const int*)  d_in[1];
    const float* W1    = (const float*)d_in[2];
    const float* asrc1 = (const float*)d_in[3];
    const float* adst1 = (const float*)d_in[4];
    const float* b1    = (const float*)d_in[5];
    const float* W2    = (const float*)d_in[6];
    const float* asrc2 = (const float*)d_in[7];
    const float* adst2 = (const float*)d_in[8];
    const float* b2    = (const float*)d_in[9];
    const float* fcw   = (const float*)d_in[10];
    const float* fcb   = (const float*)d_in[11];
    float* out = (float*)d_out;

    const int N = in_sizes[0] / 128;
    const int E = in_sizes[1] / 2;
    const int ITEMS = E + N;
    const int NB = (N + 255) >> 8;    // buckets of 256 nodes

    // workspace carve-up
    char* w = (char*)d_ws;
    size_t off = 0;
    int* deg   = (int*)(w + off); off = align256(off + (size_t)N * 4);
    int* offs  = (int*)(w + off); off = align256(off + (size_t)(N + 1) * 4);
    int* bsum  = (int*)(w + off); off = align256(off + 256 * 4);
    int* bCnt  = (int*)(w + off); off = align256(off + 512 * 4);
    int* bOff  = (int*)(w + off); off = align256(off + 512 * 4);
    int* bFill = (int*)(w + off); off = align256(off + 512 * 4);
    int* csr   = (int*)(w + off); off = align256(off + (size_t)ITEMS * 4);
    int2* binned = (int2*)(w + off); off = align256(off + (size_t)ITEMS * 8);
    float* As = (float*)(w + off); off = align256(off + (size_t)N * 4 * 4);
    float* Ad = (float*)(w + off); off = align256(off + (size_t)N * 4 * 4);
    float* g  = (float*)(w + off); off = align256(off + 66 * 4);
    unsigned short* bufH = (unsigned short*)(w + off); off = align256(off + (size_t)N * 128 * 2);
    unsigned short* bufO = (unsigned short*)(w + off); off = align256(off + (size_t)N * 128 * 4);
    float* out2 = (float*)bufO;   // layer-2 output aliases bufO (fp32, N x 64)

    const int nb = (N + 1023) / 1024;

    // --- build CSR (by dst, self loops included) ---
    init_k<<<1, 512, 0, stream>>>(bCnt, g);
    bucket_hist_k<<<1024, 256, 0, stream>>>(ei, bCnt, E, N, NB);
    bucket_scan_k<<<1, 512, 0, stream>>>(bCnt, bOff, bFill, NB);
    bin_scatter_k<<<(ITEMS + 4095) / 4096, 256, 0, stream>>>(ei, bFill, binned, E, N);
    node_hist_k<<<NB, 256, 0, stream>>>(binned, bOff, bCnt, deg, N);
    scan_block_k<<<nb, 1024, 0, stream>>>(deg, offs, bsum, N);
    scan_tops_k<<<1, 128, 0, stream>>>(bsum, nb);
    scan_add_k<<<(N + 255) / 256, 256, 0, stream>>>(offs, bsum, N, ITEMS);
    csr_scatter_k<<<NB, 256, 0, stream>>>(binned, bOff, bCnt, offs, csr);

    // --- layer 1 ---
    gemm_alpha_k<128, false><<<(N + 63) / 64, 256, 0, stream>>>(
        x, W1, asrc1, adst1, bufH, As, Ad, N);
    agg128_k<true><<<(N * 64 + 255) / 256, 256, 0, stream>>>(
        bufH, As, Ad, offs, csr, b1, bufO, N);

    // --- layer 2 ---
    gemm_alpha_k<64, true><<<(N + 63) / 64, 256, 0, stream>>>(
        bufO, W2, asrc2, adst2, bufH, As, Ad, N);
    agg64_k<<<(N * 64 + 255) / 256, 256, 0, stream>>>(
        bufH, As, Ad, offs, csr, b2, out2, N);

    // --- pool + fc ---
    pool_k<<<256, 256, 0, stream>>>(out2, g, N);
    fc_k<<<1, 64, 0, stream>>>(g, fcw, fcb, out);
}

// Round 6
// 309.243 us; speedup vs baseline: 2.3357x; 1.1837x over previous
//
#include <hip/hip_runtime.h>
#include <hip/hip_bf16.h>
#include <math.h>

// ---------------- bf16 helpers ----------------

__device__ __forceinline__ float b2f(unsigned short u) {
    return __uint_as_float(((unsigned)u) << 16);
}
__device__ __forceinline__ unsigned short f2b(float f) {
    unsigned x = __float_as_uint(f);
    return (unsigned short)((x + 0x7fffu + ((x >> 16) & 1u)) >> 16);  // RNE
}

struct alignas(16) us8 { unsigned short v[8]; };

typedef __attribute__((ext_vector_type(8))) short short8v;   // 8 bf16 (4 VGPRs)
typedef __attribute__((ext_vector_type(4))) float f32x4;     // MFMA accumulator

// ================= CSR build: bucket-binned counting sort =================
// Items 0..E-1 are edges (src=ei[i], dst=ei[E+i]); items E..E+N-1 are self loops.
// Bucket b = dst >> 8. All per-node atomics in LDS; csr writes confined to one
// bucket's window per block (lines fully populated before writeback).

__global__ void init_k(int* __restrict__ bucketCnt, float* __restrict__ g) {
    int i = threadIdx.x;
    if (i < 512) bucketCnt[i] = 0;
    if (i < 66)  g[i] = 0.f;
}

__global__ void bucket_hist_k(const int* __restrict__ ei, int* __restrict__ bucketCnt,
                              int E, int N, int NB) {
    __shared__ int cnt[512];
    for (int t = threadIdx.x; t < 512; t += blockDim.x) cnt[t] = 0;
    __syncthreads();
    const int ITEMS = E + N;
    for (int i = blockIdx.x * blockDim.x + threadIdx.x; i < ITEMS;
         i += gridDim.x * blockDim.x) {
        int d = (i < E) ? ei[E + i] : (i - E);
        atomicAdd(&cnt[d >> 8], 1);
    }
    __syncthreads();
    for (int t = threadIdx.x; t < NB; t += blockDim.x)
        if (cnt[t]) atomicAdd(&bucketCnt[t], cnt[t]);
}

__global__ void bucket_scan_k(const int* __restrict__ bucketCnt,
                              int* __restrict__ bucketOff,
                              int* __restrict__ bucketFill, int NB) {
    __shared__ int ls[512];
    int t = threadIdx.x;
    int v = (t < NB) ? bucketCnt[t] : 0;
    ls[t] = v;
    __syncthreads();
    for (int off = 1; off < 512; off <<= 1) {
        int a = (t >= off) ? ls[t - off] : 0;
        __syncthreads();
        ls[t] += a;
        __syncthreads();
    }
    if (t < NB) { int e = ls[t] - v; bucketOff[t] = e; bucketFill[t] = e; }
}

__global__ __launch_bounds__(256) void bin_scatter_k(const int* __restrict__ ei,
                                                     int* __restrict__ bucketFill,
                                                     int2* __restrict__ binned,
                                                     int E, int N) {
    __shared__ int cnt[512];
    __shared__ int base[512];
    const int ITEMS = E + N;
    const int t = threadIdx.x;
    const int chunk0 = blockIdx.x * 4096;
    for (int b = t; b < 512; b += 256) cnt[b] = 0;
    __syncthreads();
    int s[16], d[16], r[16];
#pragma unroll
    for (int j = 0; j < 16; j++) {
        int i = chunk0 + j * 256 + t;
        if (i < ITEMS) {
            if (i < E) { s[j] = ei[i]; d[j] = ei[E + i]; }
            else       { s[j] = d[j] = i - E; }
            r[j] = atomicAdd(&cnt[d[j] >> 8], 1);
        } else d[j] = -1;
    }
    __syncthreads();
    for (int b = t; b < 512; b += 256) {
        int c = cnt[b];
        base[b] = c ? atomicAdd(&bucketFill[b], c) : 0;
    }
    __syncthreads();
#pragma unroll
    for (int j = 0; j < 16; j++)
        if (d[j] >= 0) binned[base[d[j] >> 8] + r[j]] = make_int2(s[j], d[j]);
}

__global__ void node_hist_k(const int2* __restrict__ binned,
                            const int* __restrict__ bucketOff,
                            const int* __restrict__ bucketCnt,
                            int* __restrict__ deg, int N) {
    __shared__ int cnt[256];
    const int b = blockIdx.x;
    cnt[threadIdx.x] = 0;
    __syncthreads();
    const int beg = bucketOff[b], c = bucketCnt[b];
    for (int i = threadIdx.x; i < c; i += 256) {
        int2 sd = binned[beg + i];
        atomicAdd(&cnt[sd.y & 255], 1);
    }
    __syncthreads();
    int node = b * 256 + threadIdx.x;
    if (node < N) deg[node] = cnt[threadIdx.x];
}

// ---------------- node-degree exclusive scan ----------------

__global__ void scan_block_k(const int* __restrict__ deg, int* __restrict__ offs,
                             int* __restrict__ bsum, int n) {
    __shared__ int ls[1024];
    int t = threadIdx.x;
    int i = blockIdx.x * 1024 + t;
    int v = (i < n) ? deg[i] : 0;
    ls[t] = v;
    __syncthreads();
    for (int off = 1; off < 1024; off <<= 1) {
        int add = (t >= off) ? ls[t - off] : 0;
        __syncthreads();
        ls[t] += add;
        __syncthreads();
    }
    if (i < n) offs[i] = ls[t] - v;
    if (t == 1023) bsum[blockIdx.x] = ls[1023];
}

__global__ void scan_tops_k(int* __restrict__ bsum, int nb) {
    __shared__ int ls[128];
    int t = threadIdx.x;
    int v = (t < nb) ? bsum[t] : 0;
    ls[t] = v;
    __syncthreads();
    for (int off = 1; off < 128; off <<= 1) {
        int add = (t >= off) ? ls[t - off] : 0;
        __syncthreads();
        ls[t] += add;
        __syncthreads();
    }
    if (t < nb) bsum[t] = ls[t] - v;
}

__global__ void scan_add_k(int* __restrict__ offs, const int* __restrict__ bsum,
                           int n, int total) {
    int i = blockIdx.x * blockDim.x + threadIdx.x;
    if (i < n) offs[i] += bsum[i >> 10];
    if (i == 0) offs[n] = total;
}

__global__ void csr_scatter_k(const int2* __restrict__ binned,
                              const int* __restrict__ bucketOff,
                              const int* __restrict__ bucketCnt,
                              const int* __restrict__ offs, int* __restrict__ csr) {
    __shared__ int fill[256];
    const int b = blockIdx.x;
    fill[threadIdx.x] = 0;
    __syncthreads();
    const int beg = bucketOff[b], c = bucketCnt[b];
    for (int i = threadIdx.x; i < c; i += 256) {
        int2 sd = binned[beg + i];
        int r = atomicAdd(&fill[sd.y & 255], 1);
        csr[offs[sd.y] + r] = sd.x;
    }
}

// ======= MFMA GEMM: Y[M,NCOL](bf16) = X[M,128] @ W[128,NCOL] + fused alpha =======
// v_mfma_f32_16x16x32_bf16 fragment layouts (cdna4_isa §10, m89-verified C/D):
//   A: lane l holds A[l&15][(l>>4)*8 + j], j=0..7
//   B: lane l holds B[(l>>4)*8 + j][l&15]
//   D: lane l, reg j -> row (l>>4)*4+j, col l&15
// A/B staged to LDS in fragment-contiguous order -> all reads are lane-contiguous
// ds_read_b128 (conflict-free, m97 pattern). Block = 64 rows x NCOL, 4 waves,
// wave w owns rows 16w..16w+15.

template<int NCOL, bool XBF16>
__global__ __launch_bounds__(256) void gemm_alpha_mfma(
        const void* __restrict__ Xv, const float* __restrict__ W,
        const float* __restrict__ asrc, const float* __restrict__ adst,
        unsigned short* __restrict__ Y, float* __restrict__ As,
        float* __restrict__ Ad, int M) {
    constexpr int NT = NCOL / 16;            // 8 (layer1) or 4 (layer2)
    __shared__ alignas(16) short alds[4 * 4 * 64 * 8];      // [w][ks][lane][8]
    __shared__ alignas(16) short blds[NT * 4 * 64 * 8];     // [nt][ks][lane][8]

    const int t    = threadIdx.x;
    const int w    = t >> 6, lane = t & 63;
    const int row0 = blockIdx.x * 64;

    // ---- stage A tile (64 x 128) as bf16 fragments ----
    if constexpr (!XBF16) {
        const float* X = (const float*)Xv;
#pragma unroll
        for (int i = 0; i < 8; i++) {
            int flat = (i * 256 + t) * 4;
            int r = flat >> 7, k0 = flat & 127;
            int gr = row0 + r;
            float4 v = make_float4(0.f, 0.f, 0.f, 0.f);
            if (gr < M) v = *(const float4*)&X[(size_t)gr * 128 + k0];
            ushort4 u;
            u.x = f2b(v.x); u.y = f2b(v.y); u.z = f2b(v.z); u.w = f2b(v.w);
            int frag = ((r >> 4) * 4 + (k0 >> 5)) * 64 + ((((k0 & 31) >> 3) << 4) | (r & 15));
            *(ushort4*)&alds[frag * 8 + (k0 & 7)] = u;
        }
    } else {
        const unsigned short* X = (const unsigned short*)Xv;
#pragma unroll
        for (int i = 0; i < 4; i++) {
            int flat = (i * 256 + t) * 8;
            int r = flat >> 7, k0 = flat & 127;
            int gr = row0 + r;
            us8 v = {};
            if (gr < M) v = *(const us8*)&X[(size_t)gr * 128 + k0];
            int frag = ((r >> 4) * 4 + (k0 >> 5)) * 64 + ((((k0 & 31) >> 3) << 4) | (r & 15));
            *(us8*)&alds[frag * 8] = v;   // k0 % 8 == 0
        }
    }

    // ---- stage B (W: 128 x NCOL fp32) as bf16 fragments ----
    {
        constexpr int KQ = 256 / NCOL;       // 2 or 4 k-quads covered per pass
        constexpr int BITER = 32 / KQ;       // 16 or 8 iterations
        int c = t % NCOL, kq = t / NCOL;
        int nt = c >> 4, n = c & 15;
#pragma unroll
        for (int i = 0; i < BITER; i++) {
            int k0 = (i * KQ + kq) * 4;
            ushort4 u;
            u.x = f2b(W[(size_t)(k0 + 0) * NCOL + c]);
            u.y = f2b(W[(size_t)(k0 + 1) * NCOL + c]);
            u.z = f2b(W[(size_t)(k0 + 2) * NCOL + c]);
            u.w = f2b(W[(size_t)(k0 + 3) * NCOL + c]);
            int frag = (nt * 4 + (k0 >> 5)) * 64 + ((((k0 & 31) >> 3) << 4) | n);
            *(ushort4*)&blds[frag * 8 + (k0 & 7)] = u;
        }
    }
    __syncthreads();

    // ---- MFMA: 16 rows x NCOL per wave ----
    f32x4 acc[NT];
#pragma unroll
    for (int nt = 0; nt < NT; nt++) acc[nt] = (f32x4){0.f, 0.f, 0.f, 0.f};
#pragma unroll
    for (int ks = 0; ks < 4; ks++) {
        short8v a = *(short8v*)&alds[((w * 4 + ks) * 64 + lane) * 8];
#pragma unroll
        for (int nt = 0; nt < NT; nt++) {
            short8v b = *(short8v*)&blds[((nt * 4 + ks) * 64 + lane) * 8];
            acc[nt] = __builtin_amdgcn_mfma_f32_16x16x32_bf16(a, b, acc[nt], 0, 0, 0);
        }
    }

    // ---- epilogue: bf16 store + alpha dots ----
    const int g = lane >> 4, col = lane & 15;
    float ps[4][4] = {}, pd[4][4] = {};      // [reg j][head]
#pragma unroll
    for (int nt = 0; nt < NT; nt++) {
        float av = asrc[nt * 16 + col];
        float dv = adst[nt * 16 + col];
        int h = (NCOL == 128) ? (nt >> 1) : nt;
#pragma unroll
        for (int j = 0; j < 4; j++) {
            float v = acc[nt][j];
            ps[j][h] = fmaf(v, av, ps[j][h]);
            pd[j][h] = fmaf(v, dv, pd[j][h]);
            int gr = row0 + w * 16 + 4 * g + j;
            if (gr < M) Y[(size_t)gr * NCOL + nt * 16 + col] = f2b(v);
        }
    }
#pragma unroll
    for (int m = 1; m < 16; m <<= 1) {
#pragma unroll
        for (int j = 0; j < 4; j++)
#pragma unroll
            for (int h = 0; h < 4; h++) {
                ps[j][h] += __shfl_xor(ps[j][h], m);
                pd[j][h] += __shfl_xor(pd[j][h], m);
            }
    }
    if (col == 0) {
#pragma unroll
        for (int j = 0; j < 4; j++) {
            int gr = row0 + w * 16 + 4 * g + j;
            if (gr < M) {
#pragma unroll
                for (int h = 0; h < 4; h++) {
                    As[gr * 4 + h] = ps[j][h];
                    Ad[gr * 4 + h] = pd[j][h];
                }
            }
        }
    }
}

// ------- aggregation: one wave per dst node ----------------------------------
// out[i] = ( sum_{e:dst=i} exp(leaky(As[src]+Ad[i])) * h[src] ) / sum exp(...)
// (segment-max dropped: softmax ratio invariant; |e| small -> fp32-safe)

template<bool RELU>
__global__ void agg128_k(const unsigned short* __restrict__ Hb,
                         const float* __restrict__ As, const float* __restrict__ Ad,
                         const int* __restrict__ offs, const int* __restrict__ csr,
                         const float* __restrict__ bias,
                         unsigned short* __restrict__ Outb, int n) {
    int wid  = (blockIdx.x * blockDim.x + threadIdx.x) >> 6;
    int lane = threadIdx.x & 63;
    if (wid >= n) return;
    const int g = lane >> 4;          // edge slot (0..3)
    const int q = lane & 15;          // channel octet
    const int head = q >> 2;
    const int beg = offs[wid], end = offs[wid + 1];
    const float ad = Ad[wid * 4 + head];
    float acc[8];
#pragma unroll
    for (int k = 0; k < 8; k++) acc[k] = 0.f;
    float sw = 0.f;

    for (int cb = beg; cb < end; cb += 64) {
        const int nc = min(64, end - cb);
        const int sreg = csr[cb + (lane < nc ? lane : 0)];
        const int ncr = (nc + 3) & ~3;
        for (int j = g; j < ncr; j += 4) {
            const bool valid = j < nc;
            const int s = __shfl(sreg, valid ? j : 0);
            float ev = As[s * 4 + head] + ad;
            ev = ev > 0.f ? ev : 0.2f * ev;
            const float w = valid ? __expf(ev) : 0.f;
            const us8 hv = *(const us8*)&Hb[(size_t)s * 128 + q * 8];
            sw += w;
#pragma unroll
            for (int k = 0; k < 8; k++) acc[k] = fmaf(w, b2f(hv.v[k]), acc[k]);
        }
    }

    sw += __shfl_xor(sw, 16); sw += __shfl_xor(sw, 32);
#pragma unroll
    for (int k = 0; k < 8; k++) {
        acc[k] += __shfl_xor(acc[k], 16);
        acc[k] += __shfl_xor(acc[k], 32);
    }
    if (g == 0) {
        const float inv = 1.f / sw;
        us8 o;
#pragma unroll
        for (int k = 0; k < 8; k++) {
            float v = fmaf(acc[k], inv, bias[q * 8 + k]);
            if (RELU) v = fmaxf(v, 0.f);
            o.v[k] = f2b(v);
        }
        *(us8*)&Outb[(size_t)wid * 128 + q * 8] = o;
    }
}

__global__ void agg64_k(const unsigned short* __restrict__ Hb,
                        const float* __restrict__ As, const float* __restrict__ Ad,
                        const int* __restrict__ offs, const int* __restrict__ csr,
                        const float* __restrict__ bias,
                        float* __restrict__ Out, int n) {
    int wid  = (blockIdx.x * blockDim.x + threadIdx.x) >> 6;
    int lane = threadIdx.x & 63;
    if (wid >= n) return;
    const int g = lane >> 3;          // edge slot (0..7)
    const int q = lane & 7;           // channel octet
    const int head = q >> 1;
    const int beg = offs[wid], end = offs[wid + 1];
    const float ad = Ad[wid * 4 + head];
    float acc[8];
#pragma unroll
    for (int k = 0; k < 8; k++) acc[k] = 0.f;
    float sw = 0.f;

    for (int cb = beg; cb < end; cb += 64) {
        const int nc = min(64, end - cb);
        const int sreg = csr[cb + (lane < nc ? lane : 0)];
        const int ncr = (nc + 7) & ~7;
        for (int j = g; j < ncr; j += 8) {
            const bool valid = j < nc;
            const int s = __shfl(sreg, valid ? j : 0);
            float ev = As[s * 4 + head] + ad;
            ev = ev > 0.f ? ev : 0.2f * ev;
            const float w = valid ? __expf(ev) : 0.f;
            const us8 hv = *(const us8*)&Hb[(size_t)s * 64 + q * 8];
            sw += w;
#pragma unroll
            for (int k = 0; k < 8; k++) acc[k] = fmaf(w, b2f(hv.v[k]), acc[k]);
        }
    }

    sw += __shfl_xor(sw, 8); sw += __shfl_xor(sw, 16); sw += __shfl_xor(sw, 32);
#pragma unroll
    for (int k = 0; k < 8; k++) {
        acc[k] += __shfl_xor(acc[k], 8);
        acc[k] += __shfl_xor(acc[k], 16);
        acc[k] += __shfl_xor(acc[k], 32);
    }
    if (g == 0) {
        const float inv = 1.f / sw;
        float4 o0, o1;
        o0.x = fmaf(acc[0], inv, bias[q * 8 + 0]);
        o0.y = fmaf(acc[1], inv, bias[q * 8 + 1]);
        o0.z = fmaf(acc[2], inv, bias[q * 8 + 2]);
        o0.w = fmaf(acc[3], inv, bias[q * 8 + 3]);
        o1.x = fmaf(acc[4], inv, bias[q * 8 + 4]);
        o1.y = fmaf(acc[5], inv, bias[q * 8 + 5]);
        o1.z = fmaf(acc[6], inv, bias[q * 8 + 6]);
        o1.w = fmaf(acc[7], inv, bias[q * 8 + 7]);
        *(float4*)&Out[(size_t)wid * 64 + q * 8]     = o0;
        *(float4*)&Out[(size_t)wid * 64 + q * 8 + 4] = o1;
    }
}

// ---------------- global add pool + FC ----------------

__global__ void pool_k(const float* __restrict__ h2, float* __restrict__ g, int n) {
    __shared__ float ls[256];
    int c   = threadIdx.x & 63;
    int rg  = (blockIdx.x * blockDim.x + threadIdx.x) >> 6;
    int nrg = (gridDim.x * blockDim.x) >> 6;
    float acc = 0.f;
    for (int r = rg; r < n; r += nrg) acc += h2[(size_t)r * 64 + c];
    ls[threadIdx.x] = acc;
    __syncthreads();
    if (threadIdx.x < 64) {
        float v = ls[threadIdx.x] + ls[threadIdx.x + 64] +
                  ls[threadIdx.x + 128] + ls[threadIdx.x + 192];
        atomicAdd(&g[c], v);
    }
}

__global__ void fc_k(const float* __restrict__ g, const float* __restrict__ w,
                     const float* __restrict__ b, float* __restrict__ out) {
    int j = threadIdx.x;
    if (j < 2) {
        float acc = b[j];
        for (int c = 0; c < 64; c++) acc = fmaf(g[c], w[c * 2 + j], acc);
        out[j] = acc;
    }
}

// ---------------- launch ----------------

static inline size_t align256(size_t x) { return (x + 255) & ~(size_t)255; }

extern "C" void kernel_launch(void* const* d_in, const int* in_sizes, int n_in,
                              void* d_out, int out_size, void* d_ws, size_t ws_size,
                              hipStream_t stream) {
    const float* x     = (const float*)d_in[0];
    const int*   ei    = (const int*)  d_in[1];
    const float* W1    = (const float*)d_in[2];
    const float* asrc1 = (const float*)d_in[3];
    const float* adst1 = (const float*)d_in[4];
    const float* b1    = (const float*)d_in[5];
    const float* W2    = (const float*)d_in[6];
    const float* asrc2 = (const float*)d_in[7];
    const float* adst2 = (const float*)d_in[8];
    const float* b2    = (const float*)d_in[9];
    const float* fcw   = (const float*)d_in[10];
    const float* fcb   = (const float*)d_in[11];
    float* out = (float*)d_out;

    const int N = in_sizes[0] / 128;
    const int E = in_sizes[1] / 2;
    const int ITEMS = E + N;
    const int NB = (N + 255) >> 8;

    // workspace carve-up
    char* w = (char*)d_ws;
    size_t off = 0;
    int* deg   = (int*)(w + off); off = align256(off + (size_t)N * 4);
    int* offs  = (int*)(w + off); off = align256(off + (size_t)(N + 1) * 4);
    int* bsum  = (int*)(w + off); off = align256(off + 256 * 4);
    int* bCnt  = (int*)(w + off); off = align256(off + 512 * 4);
    int* bOff  = (int*)(w + off); off = align256(off + 512 * 4);
    int* bFill = (int*)(w + off); off = align256(off + 512 * 4);
    int* csr   = (int*)(w + off); off = align256(off + (size_t)ITEMS * 4);
    int2* binned = (int2*)(w + off); off = align256(off + (size_t)ITEMS * 8);
    float* As = (float*)(w + off); off = align256(off + (size_t)N * 4 * 4);
    float* Ad = (float*)(w + off); off = align256(off + (size_t)N * 4 * 4);
    float* g  = (float*)(w + off); off = align256(off + 66 * 4);
    unsigned short* bufH = (unsigned short*)(w + off); off = align256(off + (size_t)N * 128 * 2);
    unsigned short* bufO = (unsigned short*)(w + off); off = align256(off + (size_t)N * 128 * 4);
    float* out2 = (float*)bufO;   // layer-2 output aliases bufO (fp32, N x 64)

    const int nb = (N + 1023) / 1024;

    // --- build CSR (by dst, self loops included) ---
    init_k<<<1, 512, 0, stream>>>(bCnt, g);
    bucket_hist_k<<<1024, 256, 0, stream>>>(ei, bCnt, E, N, NB);
    bucket_scan_k<<<1, 512, 0, stream>>>(bCnt, bOff, bFill, NB);
    bin_scatter_k<<<(ITEMS + 4095) / 4096, 256, 0, stream>>>(ei, bFill, binned, E, N);
    node_hist_k<<<NB, 256, 0, stream>>>(binned, bOff, bCnt, deg, N);
    scan_block_k<<<nb, 1024, 0, stream>>>(deg, offs, bsum, N);
    scan_tops_k<<<1, 128, 0, stream>>>(bsum, nb);
    scan_add_k<<<(N + 255) / 256, 256, 0, stream>>>(offs, bsum, N, ITEMS);
    csr_scatter_k<<<NB, 256, 0, stream>>>(binned, bOff, bCnt, offs, csr);

    // --- layer 1 ---
    gemm_alpha_mfma<128, false><<<(N + 63) / 64, 256, 0, stream>>>(
        x, W1, asrc1, adst1, bufH, As, Ad, N);
    agg128_k<true><<<(N * 64 + 255) / 256, 256, 0, stream>>>(
        bufH, As, Ad, offs, csr, b1, bufO, N);

    // --- layer 2 ---
    gemm_alpha_mfma<64, true><<<(N + 63) / 64, 256, 0, stream>>>(
        bufO, W2, asrc2, adst2, bufH, As, Ad, N);
    agg64_k<<<(N * 64 + 255) / 256, 256, 0, stream>>>(
        bufH, As, Ad, offs, csr, b2, out2, N);

    // --- pool + fc ---
    pool_k<<<256, 256, 0, stream>>>(out2, g, N);
    fc_k<<<1, 64, 0, stream>>>(g, fcw, fcb, out);
}

// Round 7
// 279.413 us; speedup vs baseline: 2.5850x; 1.1068x over previous
//
#include <hip/hip_runtime.h>
#include <hip/hip_bf16.h>
#include <math.h>

// ---------------- bf16 helpers ----------------

__device__ __forceinline__ float b2f(unsigned short u) {
    return __uint_as_float(((unsigned)u) << 16);
}
__device__ __forceinline__ unsigned short f2b(float f) {
    unsigned x = __float_as_uint(f);
    return (unsigned short)((x + 0x7fffu + ((x >> 16) & 1u)) >> 16);  // RNE
}

struct alignas(16) us8 { unsigned short v[8]; };

typedef __attribute__((ext_vector_type(8))) short short8v;   // 8 bf16 (4 VGPRs)
typedef __attribute__((ext_vector_type(4))) float f32x4;     // MFMA accumulator

// ================= CSR build: bucket-binned counting sort =================
// Items 0..E-1 are edges (src=ei[i], dst=ei[E+i]); items E..E+N-1 are self loops.
// Bucket b = dst >> 8. All per-node atomics in LDS; csr writes confined to one
// bucket's window per block (lines fully populated before writeback).

__global__ void init_k(int* __restrict__ bucketCnt, float* __restrict__ g) {
    int i = threadIdx.x;
    if (i < 512) bucketCnt[i] = 0;
    if (i < 66)  g[i] = 0.f;
}

__global__ void bucket_hist_k(const int* __restrict__ ei, int* __restrict__ bucketCnt,
                              int E, int N, int NB) {
    __shared__ int cnt[512];
    for (int t = threadIdx.x; t < 512; t += blockDim.x) cnt[t] = 0;
    __syncthreads();
    const int ITEMS = E + N;
    for (int i = blockIdx.x * blockDim.x + threadIdx.x; i < ITEMS;
         i += gridDim.x * blockDim.x) {
        int d = (i < E) ? ei[E + i] : (i - E);
        atomicAdd(&cnt[d >> 8], 1);
    }
    __syncthreads();
    for (int t = threadIdx.x; t < NB; t += blockDim.x)
        if (cnt[t]) atomicAdd(&bucketCnt[t], cnt[t]);
}

__global__ void bucket_scan_k(const int* __restrict__ bucketCnt,
                              int* __restrict__ bucketOff,
                              int* __restrict__ bucketFill, int NB) {
    __shared__ int ls[512];
    int t = threadIdx.x;
    int v = (t < NB) ? bucketCnt[t] : 0;
    ls[t] = v;
    __syncthreads();
    for (int off = 1; off < 512; off <<= 1) {
        int a = (t >= off) ? ls[t - off] : 0;
        __syncthreads();
        ls[t] += a;
        __syncthreads();
    }
    if (t < NB) { int e = ls[t] - v; bucketOff[t] = e; bucketFill[t] = e; }
}

__global__ __launch_bounds__(256) void bin_scatter_k(const int* __restrict__ ei,
                                                     int* __restrict__ bucketFill,
                                                     int2* __restrict__ binned,
                                                     int E, int N) {
    __shared__ int cnt[512];
    __shared__ int base[512];
    const int ITEMS = E + N;
    const int t = threadIdx.x;
    const int chunk0 = blockIdx.x * 4096;
    for (int b = t; b < 512; b += 256) cnt[b] = 0;
    __syncthreads();
    int s[16], d[16], r[16];
#pragma unroll
    for (int j = 0; j < 16; j++) {
        int i = chunk0 + j * 256 + t;
        if (i < ITEMS) {
            if (i < E) { s[j] = ei[i]; d[j] = ei[E + i]; }
            else       { s[j] = d[j] = i - E; }
            r[j] = atomicAdd(&cnt[d[j] >> 8], 1);
        } else d[j] = -1;
    }
    __syncthreads();
    for (int b = t; b < 512; b += 256) {
        int c = cnt[b];
        base[b] = c ? atomicAdd(&bucketFill[b], c) : 0;
    }
    __syncthreads();
#pragma unroll
    for (int j = 0; j < 16; j++)
        if (d[j] >= 0) binned[base[d[j] >> 8] + r[j]] = make_int2(s[j], d[j]);
}

// fused per-bucket node histogram + LDS scan -> offs written directly
// (bucket-local offsets, so no global scan chain needed)
__global__ void node_offs_k(const int2* __restrict__ binned,
                            const int* __restrict__ bucketOff,
                            const int* __restrict__ bucketCnt,
                            int* __restrict__ offs, int N, int ITEMS) {
    __shared__ int cnt[256];
    __shared__ int ls[256];
    const int b = blockIdx.x;
    const int t = threadIdx.x;
    cnt[t] = 0;
    __syncthreads();
    const int beg = bucketOff[b], c = bucketCnt[b];
    for (int i = t; i < c; i += 256)
        atomicAdd(&cnt[binned[beg + i].y & 255], 1);
    __syncthreads();
    int v = cnt[t];
    ls[t] = v;
    __syncthreads();
    for (int off = 1; off < 256; off <<= 1) {
        int a = (t >= off) ? ls[t - off] : 0;
        __syncthreads();
        ls[t] += a;
        __syncthreads();
    }
    int node = b * 256 + t;
    if (node < N) offs[node] = beg + ls[t] - v;
    if (node == N - 1) offs[N] = ITEMS;
}

__global__ void csr_scatter_k(const int2* __restrict__ binned,
                              const int* __restrict__ bucketOff,
                              const int* __restrict__ bucketCnt,
                              const int* __restrict__ offs, int* __restrict__ csr) {
    __shared__ int fill[256];
    const int b = blockIdx.x;
    fill[threadIdx.x] = 0;
    __syncthreads();
    const int beg = bucketOff[b], c = bucketCnt[b];
    for (int i = threadIdx.x; i < c; i += 256) {
        int2 sd = binned[beg + i];
        int r = atomicAdd(&fill[sd.y & 255], 1);
        csr[offs[sd.y] + r] = sd.x;
    }
}

// ======= MFMA GEMM: Y[M,NCOL](bf16) = X[M,128] @ W[128,NCOL] + fused alpha =======
// v_mfma_f32_16x16x32_bf16 fragment layouts (cdna4_isa §10, m89-verified C/D):
//   A: lane l holds A[l&15][(l>>4)*8 + j];  B: lane l holds B[(l>>4)*8 + j][l&15]
//   D: lane l, reg j -> row (l>>4)*4+j, col l&15
// A/B staged to LDS in fragment-contiguous order -> lane-contiguous ds_read_b128.

template<int NCOL, bool XBF16>
__global__ __launch_bounds__(256) void gemm_alpha_mfma(
        const void* __restrict__ Xv, const float* __restrict__ W,
        const float* __restrict__ asrc, const float* __restrict__ adst,
        unsigned short* __restrict__ Y, float* __restrict__ As,
        float* __restrict__ Ad, int M) {
    constexpr int NT = NCOL / 16;            // 8 (layer1) or 4 (layer2)
    __shared__ alignas(16) short alds[4 * 4 * 64 * 8];      // [w][ks][lane][8]
    __shared__ alignas(16) short blds[NT * 4 * 64 * 8];     // [nt][ks][lane][8]

    const int t    = threadIdx.x;
    const int w    = t >> 6, lane = t & 63;
    const int row0 = blockIdx.x * 64;

    // ---- stage A tile (64 x 128) as bf16 fragments ----
    if constexpr (!XBF16) {
        const float* X = (const float*)Xv;
#pragma unroll
        for (int i = 0; i < 8; i++) {
            int flat = (i * 256 + t) * 4;
            int r = flat >> 7, k0 = flat & 127;
            int gr = row0 + r;
            float4 v = make_float4(0.f, 0.f, 0.f, 0.f);
            if (gr < M) v = *(const float4*)&X[(size_t)gr * 128 + k0];
            ushort4 u;
            u.x = f2b(v.x); u.y = f2b(v.y); u.z = f2b(v.z); u.w = f2b(v.w);
            int frag = ((r >> 4) * 4 + (k0 >> 5)) * 64 + ((((k0 & 31) >> 3) << 4) | (r & 15));
            *(ushort4*)&alds[frag * 8 + (k0 & 7)] = u;
        }
    } else {
        const unsigned short* X = (const unsigned short*)Xv;
#pragma unroll
        for (int i = 0; i < 4; i++) {
            int flat = (i * 256 + t) * 8;
            int r = flat >> 7, k0 = flat & 127;
            int gr = row0 + r;
            us8 v = {};
            if (gr < M) v = *(const us8*)&X[(size_t)gr * 128 + k0];
            int frag = ((r >> 4) * 4 + (k0 >> 5)) * 64 + ((((k0 & 31) >> 3) << 4) | (r & 15));
            *(us8*)&alds[frag * 8] = v;   // k0 % 8 == 0
        }
    }

    // ---- stage B (W: 128 x NCOL fp32) as bf16 fragments ----
    {
        constexpr int KQ = 256 / NCOL;       // 2 or 4 k-quads covered per pass
        constexpr int BITER = 32 / KQ;       // 16 or 8 iterations
        int c = t % NCOL, kq = t / NCOL;
        int nt = c >> 4, n = c & 15;
#pragma unroll
        for (int i = 0; i < BITER; i++) {
            int k0 = (i * KQ + kq) * 4;
            ushort4 u;
            u.x = f2b(W[(size_t)(k0 + 0) * NCOL + c]);
            u.y = f2b(W[(size_t)(k0 + 1) * NCOL + c]);
            u.z = f2b(W[(size_t)(k0 + 2) * NCOL + c]);
            u.w = f2b(W[(size_t)(k0 + 3) * NCOL + c]);
            int frag = (nt * 4 + (k0 >> 5)) * 64 + ((((k0 & 31) >> 3) << 4) | n);
            *(ushort4*)&blds[frag * 8 + (k0 & 7)] = u;
        }
    }
    __syncthreads();

    // ---- MFMA: 16 rows x NCOL per wave ----
    f32x4 acc[NT];
#pragma unroll
    for (int nt = 0; nt < NT; nt++) acc[nt] = (f32x4){0.f, 0.f, 0.f, 0.f};
#pragma unroll
    for (int ks = 0; ks < 4; ks++) {
        short8v a = *(short8v*)&alds[((w * 4 + ks) * 64 + lane) * 8];
#pragma unroll
        for (int nt = 0; nt < NT; nt++) {
            short8v b = *(short8v*)&blds[((nt * 4 + ks) * 64 + lane) * 8];
            acc[nt] = __builtin_amdgcn_mfma_f32_16x16x32_bf16(a, b, acc[nt], 0, 0, 0);
        }
    }

    // ---- epilogue: bf16 store + alpha dots ----
    const int g = lane >> 4, col = lane & 15;
    float ps[4][4] = {}, pd[4][4] = {};      // [reg j][head]
#pragma unroll
    for (int nt = 0; nt < NT; nt++) {
        float av = asrc[nt * 16 + col];
        float dv = adst[nt * 16 + col];
        int h = (NCOL == 128) ? (nt >> 1) : nt;
#pragma unroll
        for (int j = 0; j < 4; j++) {
            float v = acc[nt][j];
            ps[j][h] = fmaf(v, av, ps[j][h]);
            pd[j][h] = fmaf(v, dv, pd[j][h]);
            int gr = row0 + w * 16 + 4 * g + j;
            if (gr < M) Y[(size_t)gr * NCOL + nt * 16 + col] = f2b(v);
        }
    }
#pragma unroll
    for (int m = 1; m < 16; m <<= 1) {
#pragma unroll
        for (int j = 0; j < 4; j++)
#pragma unroll
            for (int h = 0; h < 4; h++) {
                ps[j][h] += __shfl_xor(ps[j][h], m);
                pd[j][h] += __shfl_xor(pd[j][h], m);
            }
    }
    if (col == 0) {
#pragma unroll
        for (int j = 0; j < 4; j++) {
            int gr = row0 + w * 16 + 4 * g + j;
            if (gr < M) {
#pragma unroll
                for (int h = 0; h < 4; h++) {
                    As[gr * 4 + h] = ps[j][h];
                    Ad[gr * 4 + h] = pd[j][h];
                }
            }
        }
    }
}

// ------- aggregation: one wave per dst node ----------------------------------
// out[i] = ( sum_{e:dst=i} exp(leaky(As[src]+Ad[i])) * h[src] ) / sum exp(...)
// (segment-max dropped: softmax ratio invariant; |e| small -> fp32-safe)
// v4: 64 srcs preloaded per wave; each lane handles TWO edges per iteration ->
// 8 (agg128) / 16 (agg64) independent 16B gathers in flight per wave.

template<bool RELU>
__global__ void agg128_k(const unsigned short* __restrict__ Hb,
                         const float* __restrict__ As, const float* __restrict__ Ad,
                         const int* __restrict__ offs, const int* __restrict__ csr,
                         const float* __restrict__ bias,
                         unsigned short* __restrict__ Outb, int n) {
    int wid  = (blockIdx.x * blockDim.x + threadIdx.x) >> 6;
    int lane = threadIdx.x & 63;
    if (wid >= n) return;
    const int g = lane >> 4;          // edge-slot group (0..3)
    const int q = lane & 15;          // channel octet
    const int head = q >> 2;
    const int beg = offs[wid], end = offs[wid + 1];
    const float ad = Ad[wid * 4 + head];
    float acc[8];
#pragma unroll
    for (int k = 0; k < 8; k++) acc[k] = 0.f;
    float sw = 0.f;

    for (int cb = beg; cb < end; cb += 64) {
        const int nc = min(64, end - cb);
        const int sreg = csr[cb + (lane < nc ? lane : 0)];   // 1 coalesced load
        const int ncr = (nc + 7) & ~7;
        for (int j = 0; j < ncr; j += 8) {
            const int e0 = j + g, e1 = j + g + 4;
            const bool v0 = e0 < nc, v1 = e1 < nc;
            const int s0 = __shfl(sreg, v0 ? e0 : 0);
            const int s1 = __shfl(sreg, v1 ? e1 : 0);
            const us8 h0 = *(const us8*)&Hb[(size_t)s0 * 128 + q * 8];
            const us8 h1 = *(const us8*)&Hb[(size_t)s1 * 128 + q * 8];
            float ev0 = As[s0 * 4 + head] + ad; ev0 = ev0 > 0.f ? ev0 : 0.2f * ev0;
            float ev1 = As[s1 * 4 + head] + ad; ev1 = ev1 > 0.f ? ev1 : 0.2f * ev1;
            const float w0 = v0 ? __expf(ev0) : 0.f;
            const float w1 = v1 ? __expf(ev1) : 0.f;
            sw += w0 + w1;
#pragma unroll
            for (int k = 0; k < 8; k++) {
                acc[k] = fmaf(w0, b2f(h0.v[k]), acc[k]);
                acc[k] = fmaf(w1, b2f(h1.v[k]), acc[k]);
            }
        }
    }

    sw += __shfl_xor(sw, 16); sw += __shfl_xor(sw, 32);
#pragma unroll
    for (int k = 0; k < 8; k++) {
        acc[k] += __shfl_xor(acc[k], 16);
        acc[k] += __shfl_xor(acc[k], 32);
    }
    if (g == 0) {
        const float inv = 1.f / sw;
        us8 o;
#pragma unroll
        for (int k = 0; k < 8; k++) {
            float v = fmaf(acc[k], inv, bias[q * 8 + k]);
            if (RELU) v = fmaxf(v, 0.f);
            o.v[k] = f2b(v);
        }
        *(us8*)&Outb[(size_t)wid * 128 + q * 8] = o;
    }
}

__global__ void agg64_k(const unsigned short* __restrict__ Hb,
                        const float* __restrict__ As, const float* __restrict__ Ad,
                        const int* __restrict__ offs, const int* __restrict__ csr,
                        const float* __restrict__ bias,
                        float* __restrict__ Out, int n) {
    int wid  = (blockIdx.x * blockDim.x + threadIdx.x) >> 6;
    int lane = threadIdx.x & 63;
    if (wid >= n) return;
    const int g = lane >> 3;          // edge-slot group (0..7)
    const int q = lane & 7;           // channel octet
    const int head = q >> 1;
    const int beg = offs[wid], end = offs[wid + 1];
    const float ad = Ad[wid * 4 + head];
    float acc[8];
#pragma unroll
    for (int k = 0; k < 8; k++) acc[k] = 0.f;
    float sw = 0.f;

    for (int cb = beg; cb < end; cb += 64) {
        const int nc = min(64, end - cb);
        const int sreg = csr[cb + (lane < nc ? lane : 0)];
        const int ncr = (nc + 15) & ~15;
        for (int j = 0; j < ncr; j += 16) {
            const int e0 = j + g, e1 = j + g + 8;
            const bool v0 = e0 < nc, v1 = e1 < nc;
            const int s0 = __shfl(sreg, v0 ? e0 : 0);
            const int s1 = __shfl(sreg, v1 ? e1 : 0);
            const us8 h0 = *(const us8*)&Hb[(size_t)s0 * 64 + q * 8];
            const us8 h1 = *(const us8*)&Hb[(size_t)s1 * 64 + q * 8];
            float ev0 = As[s0 * 4 + head] + ad; ev0 = ev0 > 0.f ? ev0 : 0.2f * ev0;
            float ev1 = As[s1 * 4 + head] + ad; ev1 = ev1 > 0.f ? ev1 : 0.2f * ev1;
            const float w0 = v0 ? __expf(ev0) : 0.f;
            const float w1 = v1 ? __expf(ev1) : 0.f;
            sw += w0 + w1;
#pragma unroll
            for (int k = 0; k < 8; k++) {
                acc[k] = fmaf(w0, b2f(h0.v[k]), acc[k]);
                acc[k] = fmaf(w1, b2f(h1.v[k]), acc[k]);
            }
        }
    }

    sw += __shfl_xor(sw, 8); sw += __shfl_xor(sw, 16); sw += __shfl_xor(sw, 32);
#pragma unroll
    for (int k = 0; k < 8; k++) {
        acc[k] += __shfl_xor(acc[k], 8);
        acc[k] += __shfl_xor(acc[k], 16);
        acc[k] += __shfl_xor(acc[k], 32);
    }
    if (g == 0) {
        const float inv = 1.f / sw;
        float4 o0, o1;
        o0.x = fmaf(acc[0], inv, bias[q * 8 + 0]);
        o0.y = fmaf(acc[1], inv, bias[q * 8 + 1]);
        o0.z = fmaf(acc[2], inv, bias[q * 8 + 2]);
        o0.w = fmaf(acc[3], inv, bias[q * 8 + 3]);
        o1.x = fmaf(acc[4], inv, bias[q * 8 + 4]);
        o1.y = fmaf(acc[5], inv, bias[q * 8 + 5]);
        o1.z = fmaf(acc[6], inv, bias[q * 8 + 6]);
        o1.w = fmaf(acc[7], inv, bias[q * 8 + 7]);
        *(float4*)&Out[(size_t)wid * 64 + q * 8]     = o0;
        *(float4*)&Out[(size_t)wid * 64 + q * 8 + 4] = o1;
    }
}

// ---------------- global add pool + FC ----------------

__global__ void pool_k(const float* __restrict__ h2, float* __restrict__ g, int n) {
    __shared__ float ls[256];
    int c   = threadIdx.x & 63;
    int rg  = (blockIdx.x * blockDim.x + threadIdx.x) >> 6;
    int nrg = (gridDim.x * blockDim.x) >> 6;
    float acc = 0.f;
    for (int r = rg; r < n; r += nrg) acc += h2[(size_t)r * 64 + c];
    ls[threadIdx.x] = acc;
    __syncthreads();
    if (threadIdx.x < 64) {
        float v = ls[threadIdx.x] + ls[threadIdx.x + 64] +
                  ls[threadIdx.x + 128] + ls[threadIdx.x + 192];
        atomicAdd(&g[c], v);
    }
}

__global__ void fc_k(const float* __restrict__ g, const float* __restrict__ w,
                     const float* __restrict__ b, float* __restrict__ out) {
    int j = threadIdx.x;
    if (j < 2) {
        float acc = b[j];
        for (int c = 0; c < 64; c++) acc = fmaf(g[c], w[c * 2 + j], acc);
        out[j] = acc;
    }
}

// ---------------- launch ----------------

static inline size_t align256(size_t x) { return (x + 255) & ~(size_t)255; }

extern "C" void kernel_launch(void* const* d_in, const int* in_sizes, int n_in,
                              void* d_out, int out_size, void* d_ws, size_t ws_size,
                              hipStream_t stream) {
    const float* x     = (const float*)d_in[0];
    const int*   ei    = (const int*)  d_in[1];
    const float* W1    = (const float*)d_in[2];
    const float* asrc1 = (const float*)d_in[3];
    const float* adst1 = (const float*)d_in[4];
    const float* b1    = (const float*)d_in[5];
    const float* W2    = (const float*)d_in[6];
    const float* asrc2 = (const float*)d_in[7];
    const float* adst2 = (const float*)d_in[8];
    const float* b2    = (const float*)d_in[9];
    const float* fcw   = (const float*)d_in[10];
    const float* fcb   = (const float*)d_in[11];
    float* out = (float*)d_out;

    const int N = in_sizes[0] / 128;
    const int E = in_sizes[1] / 2;
    const int ITEMS = E + N;
    const int NB = (N + 255) >> 8;

    // workspace carve-up
    char* w = (char*)d_ws;
    size_t off = 0;
    int* offs  = (int*)(w + off); off = align256(off + (size_t)(N + 1) * 4);
    int* bCnt  = (int*)(w + off); off = align256(off + 512 * 4);
    int* bOff  = (int*)(w + off); off = align256(off + 512 * 4);
    int* bFill = (int*)(w + off); off = align256(off + 512 * 4);
    int* csr   = (int*)(w + off); off = align256(off + (size_t)ITEMS * 4);
    int2* binned = (int2*)(w + off); off = align256(off + (size_t)ITEMS * 8);
    float* As = (float*)(w + off); off = align256(off + (size_t)N * 4 * 4);
    float* Ad = (float*)(w + off); off = align256(off + (size_t)N * 4 * 4);
    float* g  = (float*)(w + off); off = align256(off + 66 * 4);
    unsigned short* bufH = (unsigned short*)(w + off); off = align256(off + (size_t)N * 128 * 2);
    unsigned short* bufO = (unsigned short*)(w + off); off = align256(off + (size_t)N * 128 * 4);
    float* out2 = (float*)bufO;   // layer-2 output aliases bufO (fp32, N x 64)

    // --- build CSR (by dst, self loops included) ---
    init_k<<<1, 512, 0, stream>>>(bCnt, g);
    bucket_hist_k<<<1024, 256, 0, stream>>>(ei, bCnt, E, N, NB);
    bucket_scan_k<<<1, 512, 0, stream>>>(bCnt, bOff, bFill, NB);
    bin_scatter_k<<<(ITEMS + 4095) / 4096, 256, 0, stream>>>(ei, bFill, binned, E, N);
    node_offs_k<<<NB, 256, 0, stream>>>(binned, bOff, bCnt, offs, N, ITEMS);
    csr_scatter_k<<<NB, 256, 0, stream>>>(binned, bOff, bCnt, offs, csr);

    // --- layer 1 ---
    gemm_alpha_mfma<128, false><<<(N + 63) / 64, 256, 0, stream>>>(
        x, W1, asrc1, adst1, bufH, As, Ad, N);
    agg128_k<true><<<(N * 64 + 255) / 256, 256, 0, stream>>>(
        bufH, As, Ad, offs, csr, b1, bufO, N);

    // --- layer 2 ---
    gemm_alpha_mfma<64, true><<<(N + 63) / 64, 256, 0, stream>>>(
        bufO, W2, asrc2, adst2, bufH, As, Ad, N);
    agg64_k<<<(N * 64 + 255) / 256, 256, 0, stream>>>(
        bufH, As, Ad, offs, csr, b2, out2, N);

    // --- pool + fc ---
    pool_k<<<256, 256, 0, stream>>>(out2, g, N);
    fc_k<<<1, 64, 0, stream>>>(g, fcw, fcb, out);
}